// Round 14
// baseline (199.346 us; speedup 1.0000x reference)
//
#include <hip/hip_runtime.h>
#include <hip/hip_bf16.h>
#include <stdint.h>

typedef short short8 __attribute__((ext_vector_type(8)));
typedef float f32x4 __attribute__((ext_vector_type(4)));

#define BQ 4
#define NSEQ 2048
#define DMODEL 1024
#define NHEAD 16
#define HDIM 64
#define MTOT 8192          // BQ*NSEQ
#define QKV_LD 3072

#if __has_builtin(__builtin_amdgcn_exp2f)
#define EXP2(x) __builtin_amdgcn_exp2f(x)
#else
#define EXP2(x) exp2f(x)
#endif
#define C_SCL 0.18033688f   // 0.125 * log2(e)
#define THR_RAW 16.635532f  // 3.0 / C_SCL : defer-max threshold (P bounded by 2^3)

__device__ __forceinline__ uint16_t f2bf(float f) {
  uint32_t u = __builtin_bit_cast(uint32_t, f);
  uint32_t r = (u + 0x7FFFu + ((u >> 16) & 1u)) >> 16;
  return (uint16_t)r;
}
// hardware RNE convert (v_cvt_pk_bf16_f32 after compiler fusion)
__device__ __forceinline__ uint16_t f2bf_hw(float f) {
  __hip_bfloat16 h = __float2bfloat16(f);
  return __builtin_bit_cast(uint16_t, h);
}
__device__ __forceinline__ float bf2f(uint16_t h) {
  uint32_t u = ((uint32_t)h) << 16;
  return __builtin_bit_cast(float, u);
}

__global__ void cast_f32_bf16_k(const float* __restrict__ in, uint16_t* __restrict__ out, int n) {
  int idx = (blockIdx.x * blockDim.x + threadIdx.x) * 4;
  int stride = gridDim.x * blockDim.x * 4;
  for (int i = idx; i < n; i += stride) {
    float4 v = *reinterpret_cast<const float4*>(in + i);
    ushort4 o;
    o.x = f2bf(v.x); o.y = f2bf(v.y); o.z = f2bf(v.z); o.w = f2bf(v.w);
    *reinterpret_cast<ushort4*>(out + i) = o;
  }
}

// in [K][N] f32 row-major -> out [N][K] bf16 row-major
__global__ void transpose_cast_k(const float* __restrict__ in, uint16_t* __restrict__ out, int K, int N) {
  __shared__ float tile[32][33];
  int n0 = blockIdx.x * 32;
  int k0 = blockIdx.y * 32;
  int tx = threadIdx.x & 31;
  int ty = threadIdx.x >> 5;
#pragma unroll
  for (int r = 0; r < 4; ++r)
    tile[ty + r * 8][tx] = in[(size_t)(k0 + ty + r * 8) * N + n0 + tx];
  __syncthreads();
#pragma unroll
  for (int r = 0; r < 4; ++r)
    out[(size_t)(n0 + ty + r * 8) * K + k0 + tx] = f2bf(tile[tx][ty + r * 8]);
}

// C[M,N] = A[M,K] @ BT[N,K]^T ; A,BT bf16 row-major. 128x128 tile, BK=32.
// Staging via global_load_lds width=16 (m97 structure).
template <bool BF16_OUT>
__global__ void __launch_bounds__(256, 2)
gemm_bt_k(const uint16_t* __restrict__ A, const uint16_t* __restrict__ BT,
          void* __restrict__ Cout, const float* __restrict__ bias,
          int M, int N, int K) {
  __shared__ uint16_t As[128 * 32];
  __shared__ uint16_t Bs[128 * 32];
  const int tid = threadIdx.x;
  const int lane = tid & 63;
  const int wave = tid >> 6;
  const int wr = wave >> 1, wc = wave & 1;   // wave -> 64x64 quadrant
  const int brow = blockIdx.y * 128;
  const int bcol = blockIdx.x * 128;
  const int l16 = lane & 15;
  const int lq = lane >> 4;

  f32x4 acc[4][4];
  const f32x4 fzero = {0.f, 0.f, 0.f, 0.f};
#pragma unroll
  for (int i = 0; i < 4; ++i)
#pragma unroll
    for (int j = 0; j < 4; ++j) acc[i][j] = fzero;

  // staging: 512 16B-chunks per tile; chunk c -> row c>>2, k-off (c&3)*8; LDS linear at c*8 elems
  const int ca = tid, cb = tid + 256;
  const size_t ga0 = (size_t)(brow + (ca >> 2)) * K + (ca & 3) * 8;
  const size_t ga1 = (size_t)(brow + (cb >> 2)) * K + (cb & 3) * 8;
  const size_t gb0 = (size_t)(bcol + (ca >> 2)) * K + (ca & 3) * 8;
  const size_t gb1 = (size_t)(bcol + (cb >> 2)) * K + (cb & 3) * 8;

  for (int kt = 0; kt < K; kt += 32) {
    __builtin_amdgcn_global_load_lds(
        (const __attribute__((address_space(1))) void*)(A + ga0 + kt),
        (__attribute__((address_space(3))) void*)&As[ca * 8], 16, 0, 0);
    __builtin_amdgcn_global_load_lds(
        (const __attribute__((address_space(1))) void*)(A + ga1 + kt),
        (__attribute__((address_space(3))) void*)&As[cb * 8], 16, 0, 0);
    __builtin_amdgcn_global_load_lds(
        (const __attribute__((address_space(1))) void*)(BT + gb0 + kt),
        (__attribute__((address_space(3))) void*)&Bs[ca * 8], 16, 0, 0);
    __builtin_amdgcn_global_load_lds(
        (const __attribute__((address_space(1))) void*)(BT + gb1 + kt),
        (__attribute__((address_space(3))) void*)&Bs[cb * 8], 16, 0, 0);
    __syncthreads();   // implicit vmcnt(0) drain before barrier
    short8 af[4], bfr[4];
#pragma unroll
    for (int r = 0; r < 4; ++r) {
      af[r]  = *reinterpret_cast<const short8*>(&As[(wr * 64 + r * 16 + l16) * 32 + lq * 8]);
      bfr[r] = *reinterpret_cast<const short8*>(&Bs[(wc * 64 + r * 16 + l16) * 32 + lq * 8]);
    }
#pragma unroll
    for (int r = 0; r < 4; ++r)
#pragma unroll
      for (int c = 0; c < 4; ++c)
        acc[r][c] = __builtin_amdgcn_mfma_f32_16x16x32_bf16(af[r], bfr[c], acc[r][c], 0, 0, 0);
    __syncthreads();
  }

#pragma unroll
  for (int r = 0; r < 4; ++r) {
    const int row0 = brow + wr * 64 + r * 16 + lq * 4;
#pragma unroll
    for (int c = 0; c < 4; ++c) {
      const int col = bcol + wc * 64 + c * 16 + l16;
#pragma unroll
      for (int i = 0; i < 4; ++i) {
        if constexpr (BF16_OUT)
          reinterpret_cast<uint16_t*>(Cout)[(size_t)(row0 + i) * N + col] = f2bf(acc[r][c][i]);
        else
          reinterpret_cast<float*>(Cout)[(size_t)(row0 + i) * N + col] = acc[r][c][i] + bias[col];
      }
    }
  }
}

// Flash attention, causal. qkv [MTOT][3072] bf16 (q|k|v), partials out.
// ROUND-14: SPLIT-KV. Each q-pair block is split into two half-blocks covering
// jt in [0,mid) and [mid,ntiles), mid = p>=7 ? 8 : 16-p -> every one of 2048
// blocks does exactly 16-17 softmax calls. Halves write UNNORMALIZED partials
// (acc bf16, m/l f32); attn_merge_k combines. Mechanism: the ~85us plateau is
// a serial-chain/overlap bound (R10-R13 eliminated LDS/HBM/barrier/VALU-mask);
// this halves chain length (33->17 iters) AND doubles resident blocks (4->8/CU,
// LDS 147KB<160, VGPR 64).
// Body per iteration is UNCHANGED from round-13 (best measured).
__global__ void __launch_bounds__(256, 3)
attn_fwd_k(const uint16_t* __restrict__ qkv, uint16_t* __restrict__ ph0,
           uint16_t* __restrict__ ph1, float* __restrict__ pml) {
  const int obid = blockIdx.x;
  const int bid = (obid & 7) * 256 + (obid >> 3);   // T1: bijective, 2048 = 8*256
  const int p = bid & 15;
  const int h = (bid >> 4) & 15;
  const int half = (bid >> 8) & 1;
  const int b = bid >> 9;
  const int qtA = p;
  const int qtB = 31 - p;
  const int tid = threadIdx.x;
  const int lane = tid & 63;
  const int w = tid >> 6;
  const int l16 = lane & 15;
  const int lq = lane >> 4;

  __shared__ uint16_t Ks[64 * 72];         // [token][d], stride 72
  __shared__ uint16_t Vt[64 * 72];         // [d][sigma-permuted token], stride 72

  const int ntiles = qtB + 1;              // = 32 - p
  const int mid = (p >= 7) ? 8 : (16 - p); // balanced split: 16-17 calls per half
  const int lo = half ? mid : 0;
  const int hi = half ? ntiles : mid;

  // Q fragments for both q-tiles (row=l16, k=8*lq+j per 32-d chunk)
  short8 qaA0, qaA1, qaB0, qaB1;
  {
    const size_t baseA = ((size_t)(b * NSEQ + qtA * 64 + w * 16 + l16)) * QKV_LD + h * 64 + lq * 8;
    const size_t baseB = ((size_t)(b * NSEQ + qtB * 64 + w * 16 + l16)) * QKV_LD + h * 64 + lq * 8;
    qaA0 = *reinterpret_cast<const short8*>(qkv + baseA);
    qaA1 = *reinterpret_cast<const short8*>(qkv + baseA + 32);
    qaB0 = *reinterpret_cast<const short8*>(qkv + baseB);
    qaB1 = *reinterpret_cast<const short8*>(qkv + baseB + 32);
  }

  float mA = -1e30f, lA = 0.f, mB = -1e30f, lB = 0.f;
  f32x4 accA[4], accB[4];
  const f32x4 fzero = {0.f, 0.f, 0.f, 0.f};
#pragma unroll
  for (int i = 0; i < 4; ++i) { accA[i] = fzero; accB[i] = fzero; }

  // staging geometry: 512 chunks, chunk c -> token row c>>3, d-off (c&7)*8
  const int r0 = tid >> 3, d0 = (tid & 7) * 8;
  const int ka0 = r0 * 72 + d0;
  const int ka1 = (r0 + 32) * 72 + d0;
  const int lqt = (r0 >> 2) & 3;
  const int nc0 = r0 >> 4;
  const int m0 = d0 >> 3;
  const int jo = (nc0 & 1) * 4 + (r0 & 3);
  const int vcol0 = (((2 * lqt) ^ m0) * 8) + jo;        // token r0  -> pa0 chunk
  const int vcol1 = (((2 * lqt + 1) ^ m0) * 8) + jo;    // token r0+32 -> pa1 chunk

  short8 rk0, rk1, rv0, rv1;
  {
    const size_t g0 = ((size_t)(b * NSEQ + lo * 64 + r0)) * QKV_LD + 1024 + h * 64 + d0;
    const size_t g1 = ((size_t)(b * NSEQ + lo * 64 + r0 + 32)) * QKV_LD + 1024 + h * 64 + d0;
    rk0 = *reinterpret_cast<const short8*>(qkv + g0);
    rv0 = *reinterpret_cast<const short8*>(qkv + g0 + 1024);
    rk1 = *reinterpret_cast<const short8*>(qkv + g1);
    rv1 = *reinterpret_cast<const short8*>(qkv + g1 + 1024);
  }

#define SOFTMAX_PV(SV, M_I, L_I, ACC, DIAG)                                     \
  {                                                                             \
    float tmax_ = -3e38f;                                                       \
    if (DIAG) {                                                                 \
      _Pragma("unroll") for (int nc = 0; nc < 4; ++nc) {                        \
        _Pragma("unroll") for (int i = 0; i < 4; ++i) {                         \
          float v_ = SV[nc][i];                                                 \
          if ((nc * 16 + lq * 4 + i) > (w * 16 + l16)) v_ = -3e38f;             \
          SV[nc][i] = v_;                                                       \
          tmax_ = fmaxf(tmax_, v_);                                             \
        }                                                                       \
      }                                                                         \
    } else {                                                                    \
      _Pragma("unroll") for (int nc = 0; nc < 4; ++nc)                          \
        tmax_ = fmaxf(tmax_, fmaxf(fmaxf(SV[nc][0], SV[nc][1]),                 \
                                   fmaxf(SV[nc][2], SV[nc][3])));               \
    }                                                                           \
    tmax_ = fmaxf(tmax_, __shfl_xor(tmax_, 16, 64));                            \
    tmax_ = fmaxf(tmax_, __shfl_xor(tmax_, 32, 64));                            \
    if (!__all(tmax_ <= M_I + THR_RAW)) {                                       \
      const float mn_ = fmaxf(M_I, tmax_);                                      \
      const float alpha_ = EXP2((M_I - mn_) * C_SCL);                           \
      M_I = mn_;                                                                \
      L_I *= alpha_;                                                            \
      float ab_[4];                                                             \
      _Pragma("unroll") for (int i = 0; i < 4; ++i)                             \
        ab_[i] = __shfl(alpha_, lq * 4 + i, 64);                                \
      _Pragma("unroll") for (int d4 = 0; d4 < 4; ++d4)                          \
        _Pragma("unroll") for (int i = 0; i < 4; ++i)                           \
          ACC[d4][i] *= ab_[i];                                                 \
    }                                                                           \
    const float mc_ = M_I * C_SCL;                                              \
    float rsum_ = 0.f;                                                          \
    short8 pa0_, pa1_;                                                          \
    _Pragma("unroll") for (int nc = 0; nc < 4; ++nc) {                          \
      _Pragma("unroll") for (int i = 0; i < 4; ++i) {                           \
        float pv_ = EXP2(__builtin_fmaf(SV[nc][i], C_SCL, -mc_));               \
        rsum_ += pv_;                                                           \
        uint16_t ph_ = f2bf_hw(pv_);                                            \
        if (nc < 2) pa0_[nc * 4 + i] = (short)ph_;                              \
        else        pa1_[(nc - 2) * 4 + i] = (short)ph_;                        \
      }                                                                         \
    }                                                                           \
    rsum_ += __shfl_xor(rsum_, 16, 64);                                         \
    rsum_ += __shfl_xor(rsum_, 32, 64);                                         \
    L_I += rsum_;                                                               \
    _Pragma("unroll") for (int d4 = 0; d4 < 4; ++d4) {                          \
      const int drow_ = d4 * 16 + l16;                                          \
      const int xr_ = (drow_ >> 3) & 7;                                         \
      short8 vb0_ = *reinterpret_cast<const short8*>(&Vt[drow_ * 72 + (((2 * lq) ^ xr_) * 8)]); \
      short8 vb1_ = *reinterpret_cast<const short8*>(&Vt[drow_ * 72 + (((2 * lq + 1) ^ xr_) * 8)]); \
      ACC[d4] = __builtin_amdgcn_mfma_f32_16x16x32_bf16(pa0_, vb0_, ACC[d4], 0, 0, 0); \
      ACC[d4] = __builtin_amdgcn_mfma_f32_16x16x32_bf16(pa1_, vb1_, ACC[d4], 0, 0, 0); \
    }                                                                           \
  }

  for (int jt = lo; jt < hi; ++jt) {
    // --- commit staged regs to LDS (prev compute finished at loop-end barrier) ---
    *reinterpret_cast<short8*>(&Ks[ka0]) = rk0;
    *reinterpret_cast<short8*>(&Ks[ka1]) = rk1;
#pragma unroll
    for (int j = 0; j < 8; ++j) Vt[(d0 + j) * 72 + vcol0] = (uint16_t)rv0[j];
#pragma unroll
    for (int j = 0; j < 8; ++j) Vt[(d0 + j) * 72 + vcol1] = (uint16_t)rv1[j];
    // --- issue next tile's global loads; latency hides under this tile's compute ---
    if (jt + 1 < hi) {
      const size_t g0 = ((size_t)(b * NSEQ + (jt + 1) * 64 + r0)) * QKV_LD + 1024 + h * 64 + d0;
      const size_t g1 = ((size_t)(b * NSEQ + (jt + 1) * 64 + r0 + 32)) * QKV_LD + 1024 + h * 64 + d0;
      rk0 = *reinterpret_cast<const short8*>(qkv + g0);
      rv0 = *reinterpret_cast<const short8*>(qkv + g0 + 1024);
      rk1 = *reinterpret_cast<const short8*>(qkv + g1);
      rv1 = *reinterpret_cast<const short8*>(qkv + g1 + 1024);
    }
    __syncthreads();

    // --- tile B: S^T = K Q^T, softmax, PV ---
    {
      f32x4 sv[4];
#pragma unroll
      for (int nc = 0; nc < 4; ++nc) {
        short8 kb0 = *reinterpret_cast<const short8*>(&Ks[(nc * 16 + l16) * 72 + lq * 8]);
        short8 kb1 = *reinterpret_cast<const short8*>(&Ks[(nc * 16 + l16) * 72 + 32 + lq * 8]);
        f32x4 s = fzero;
        s = __builtin_amdgcn_mfma_f32_16x16x32_bf16(kb0, qaB0, s, 0, 0, 0);
        s = __builtin_amdgcn_mfma_f32_16x16x32_bf16(kb1, qaB1, s, 0, 0, 0);
        sv[nc] = s;
      }
      SOFTMAX_PV(sv, mB, lB, accB, jt == qtB);
    }

    // --- tile A (active while jt <= qtA) ---
    if (jt <= qtA) {
      f32x4 sv[4];
#pragma unroll
      for (int nc = 0; nc < 4; ++nc) {
        short8 kb0 = *reinterpret_cast<const short8*>(&Ks[(nc * 16 + l16) * 72 + lq * 8]);
        short8 kb1 = *reinterpret_cast<const short8*>(&Ks[(nc * 16 + l16) * 72 + 32 + lq * 8]);
        f32x4 s = fzero;
        s = __builtin_amdgcn_mfma_f32_16x16x32_bf16(kb0, qaA0, s, 0, 0, 0);
        s = __builtin_amdgcn_mfma_f32_16x16x32_bf16(kb1, qaA1, s, 0, 0, 0);
        sv[nc] = s;
      }
      SOFTMAX_PV(sv, mA, lA, accA, jt == qtA);
    }

    __syncthreads();   // protect Ks/Vt before next stage-commit
  }

  // --- partial writeout: unnormalized acc (bf16) + per-row m,l (f32) ---
  uint16_t* ph = half ? ph1 : ph0;
  {
    const size_t orow = (size_t)(b * NSEQ) + qtA * 64 + w * 16 + lq * 4;
#pragma unroll
    for (int d4 = 0; d4 < 4; ++d4)
#pragma unroll
      for (int i = 0; i < 4; ++i)
        ph[(orow + i) * (size_t)DMODEL + h * 64 + d4 * 16 + l16] = f2bf_hw(accA[d4][i]);
  }
  {
    const size_t orow = (size_t)(b * NSEQ) + qtB * 64 + w * 16 + lq * 4;
#pragma unroll
    for (int d4 = 0; d4 < 4; ++d4)
#pragma unroll
      for (int i = 0; i < 4; ++i)
        ph[(orow + i) * (size_t)DMODEL + h * 64 + d4 * 16 + l16] = f2bf_hw(accB[d4][i]);
  }
  if (lq == 0) {
    const size_t rowA = (size_t)(b * NSEQ) + qtA * 64 + w * 16 + l16;
    const size_t rowB = (size_t)(b * NSEQ) + qtB * 64 + w * 16 + l16;
    const size_t iA = (rowA * NHEAD + h) * 4 + half * 2;
    const size_t iB = (rowB * NHEAD + h) * 4 + half * 2;
    pml[iA] = mA; pml[iA + 1] = lA;
    pml[iB] = mB; pml[iB + 1] = lB;
  }
}

// merge two KV-half partials: out = (a0*alpha0 + a1*alpha1) / (l0*alpha0 + l1*alpha1)
__global__ void attn_merge_k(const uint16_t* __restrict__ ph0, const uint16_t* __restrict__ ph1,
                             const float* __restrict__ pml, uint16_t* __restrict__ outb) {
  const size_t base = ((size_t)blockIdx.x * 256 + threadIdx.x) * 8;
  const int row = (int)(base >> 10);
  const int h = (int)((base & 1023) >> 6);
  const float4 q = *reinterpret_cast<const float4*>(pml + ((size_t)row * NHEAD + h) * 4);
  const float ms = fmaxf(q.x, q.z);
  const float a0 = EXP2((q.x - ms) * C_SCL);
  const float a1 = EXP2((q.z - ms) * C_SCL);
  const float inv = 1.f / (q.y * a0 + q.w * a1);
  short8 v0 = *reinterpret_cast<const short8*>(ph0 + base);
  short8 v1 = *reinterpret_cast<const short8*>(ph1 + base);
  short8 o;
#pragma unroll
  for (int j = 0; j < 8; ++j) {
    float f = (bf2f((uint16_t)v0[j]) * a0 + bf2f((uint16_t)v1[j]) * a1) * inv;
    o[j] = (short)f2bf_hw(f);
  }
  *reinterpret_cast<short8*>(outb + base) = o;
}

extern "C" void kernel_launch(void* const* d_in, const int* in_sizes, int n_in,
                              void* d_out, int out_size, void* d_ws, size_t ws_size,
                              hipStream_t stream) {
  const float* x      = (const float*)d_in[0];
  const float* w_attn = (const float*)d_in[1];
  const float* w_proj = (const float*)d_in[2];
  const float* b_proj = (const float*)d_in[3];

  uint16_t* xb    = (uint16_t*)d_ws;                    // [8192][1024]
  uint16_t* wat   = xb   + (size_t)MTOT * DMODEL;       // [3072][1024] (w_attn^T)
  uint16_t* wpt   = wat  + (size_t)3072 * 1024;         // [1024][1024] (w_proj^T)
  uint16_t* qkvb  = wpt  + (size_t)1024 * 1024;         // [8192][3072]
  uint16_t* attnb = qkvb + (size_t)MTOT * QKV_LD;       // [8192][1024]
  uint16_t* ph1   = attnb + (size_t)MTOT * DMODEL;      // [8192][1024] half-1 partial
  float*    pml   = (float*)(ph1 + (size_t)MTOT * DMODEL); // [8192][16][4] m0,l0,m1,l1
  uint16_t* ph0   = xb;                                 // reuse xb (dead after gemm1)

  cast_f32_bf16_k<<<2048, 256, 0, stream>>>(x, xb, MTOT * DMODEL);
  transpose_cast_k<<<dim3(3072 / 32, 1024 / 32), 256, 0, stream>>>(w_attn, wat, 1024, 3072);
  transpose_cast_k<<<dim3(1024 / 32, 1024 / 32), 256, 0, stream>>>(w_proj, wpt, 1024, 1024);

  gemm_bt_k<true><<<dim3(3072 / 128, MTOT / 128), 256, 0, stream>>>(
      xb, wat, qkvb, nullptr, MTOT, 3072, 1024);

  attn_fwd_k<<<BQ * NHEAD * 16 * 2, 256, 0, stream>>>(qkvb, ph0, ph1, pml);
  attn_merge_k<<<(MTOT * DMODEL) / (8 * 256), 256, 0, stream>>>(ph0, ph1, pml, attnb);

  gemm_bt_k<false><<<dim3(1024 / 128, MTOT / 128), 256, 0, stream>>>(
      attnb, wpt, d_out, b_proj, MTOT, 1024, 1024);
}

// Round 15
// 188.291 us; speedup vs baseline: 1.0587x; 1.0587x over previous
//
#include <hip/hip_runtime.h>
#include <hip/hip_bf16.h>
#include <stdint.h>

typedef short short8 __attribute__((ext_vector_type(8)));
typedef float f32x4 __attribute__((ext_vector_type(4)));

#define BQ 4
#define NSEQ 2048
#define DMODEL 1024
#define NHEAD 16
#define HDIM 64
#define MTOT 8192          // BQ*NSEQ
#define QKV_LD 3072

#if __has_builtin(__builtin_amdgcn_exp2f)
#define EXP2(x) __builtin_amdgcn_exp2f(x)
#else
#define EXP2(x) exp2f(x)
#endif
#define C_SCL 0.18033688f   // 0.125 * log2(e)
#define THR_RAW 16.635532f  // 3.0 / C_SCL : defer-max threshold (P bounded by 2^3)

__device__ __forceinline__ uint16_t f2bf(float f) {
  uint32_t u = __builtin_bit_cast(uint32_t, f);
  uint32_t r = (u + 0x7FFFu + ((u >> 16) & 1u)) >> 16;
  return (uint16_t)r;
}
// hardware RNE convert (v_cvt_pk_bf16_f32 after compiler fusion)
__device__ __forceinline__ uint16_t f2bf_hw(float f) {
  __hip_bfloat16 h = __float2bfloat16(f);
  return __builtin_bit_cast(uint16_t, h);
}

__global__ void cast_f32_bf16_k(const float* __restrict__ in, uint16_t* __restrict__ out, int n) {
  int idx = (blockIdx.x * blockDim.x + threadIdx.x) * 4;
  int stride = gridDim.x * blockDim.x * 4;
  for (int i = idx; i < n; i += stride) {
    float4 v = *reinterpret_cast<const float4*>(in + i);
    ushort4 o;
    o.x = f2bf(v.x); o.y = f2bf(v.y); o.z = f2bf(v.z); o.w = f2bf(v.w);
    *reinterpret_cast<ushort4*>(out + i) = o;
  }
}

// in [K][N] f32 row-major -> out [N][K] bf16 row-major
__global__ void transpose_cast_k(const float* __restrict__ in, uint16_t* __restrict__ out, int K, int N) {
  __shared__ float tile[32][33];
  int n0 = blockIdx.x * 32;
  int k0 = blockIdx.y * 32;
  int tx = threadIdx.x & 31;
  int ty = threadIdx.x >> 5;
#pragma unroll
  for (int r = 0; r < 4; ++r)
    tile[ty + r * 8][tx] = in[(size_t)(k0 + ty + r * 8) * N + n0 + tx];
  __syncthreads();
#pragma unroll
  for (int r = 0; r < 4; ++r)
    out[(size_t)(n0 + ty + r * 8) * K + k0 + tx] = f2bf(tile[tx][ty + r * 8]);
}

// C[M,N] = A[M,K] @ BT[N,K]^T ; A,BT bf16 row-major. 128x128 tile, BK=32.
// Staging via global_load_lds width=16 (m97 structure).
// ROUND-15: __launch_bounds__(256,3) — was (256,2) = 2 blocks/CU (8 waves), below
// the ~12 waves/CU where this structure measures 874-912 TF (m114: wave-level
// overlap absorbs the vmcnt(0)-before-barrier drain). VGPR est ~120 < 170 cap.
template <bool BF16_OUT>
__global__ void __launch_bounds__(256, 3)
gemm_bt_k(const uint16_t* __restrict__ A, const uint16_t* __restrict__ BT,
          void* __restrict__ Cout, const float* __restrict__ bias,
          int M, int N, int K) {
  __shared__ uint16_t As[128 * 32];
  __shared__ uint16_t Bs[128 * 32];
  const int tid = threadIdx.x;
  const int lane = tid & 63;
  const int wave = tid >> 6;
  const int wr = wave >> 1, wc = wave & 1;   // wave -> 64x64 quadrant
  const int brow = blockIdx.y * 128;
  const int bcol = blockIdx.x * 128;
  const int l16 = lane & 15;
  const int lq = lane >> 4;

  f32x4 acc[4][4];
  const f32x4 fzero = {0.f, 0.f, 0.f, 0.f};
#pragma unroll
  for (int i = 0; i < 4; ++i)
#pragma unroll
    for (int j = 0; j < 4; ++j) acc[i][j] = fzero;

  // staging: 512 16B-chunks per tile; chunk c -> row c>>2, k-off (c&3)*8; LDS linear at c*8 elems
  const int ca = tid, cb = tid + 256;
  const size_t ga0 = (size_t)(brow + (ca >> 2)) * K + (ca & 3) * 8;
  const size_t ga1 = (size_t)(brow + (cb >> 2)) * K + (cb & 3) * 8;
  const size_t gb0 = (size_t)(bcol + (ca >> 2)) * K + (ca & 3) * 8;
  const size_t gb1 = (size_t)(bcol + (cb >> 2)) * K + (cb & 3) * 8;

  for (int kt = 0; kt < K; kt += 32) {
    __builtin_amdgcn_global_load_lds(
        (const __attribute__((address_space(1))) void*)(A + ga0 + kt),
        (__attribute__((address_space(3))) void*)&As[ca * 8], 16, 0, 0);
    __builtin_amdgcn_global_load_lds(
        (const __attribute__((address_space(1))) void*)(A + ga1 + kt),
        (__attribute__((address_space(3))) void*)&As[cb * 8], 16, 0, 0);
    __builtin_amdgcn_global_load_lds(
        (const __attribute__((address_space(1))) void*)(BT + gb0 + kt),
        (__attribute__((address_space(3))) void*)&Bs[ca * 8], 16, 0, 0);
    __builtin_amdgcn_global_load_lds(
        (const __attribute__((address_space(1))) void*)(BT + gb1 + kt),
        (__attribute__((address_space(3))) void*)&Bs[cb * 8], 16, 0, 0);
    __syncthreads();   // implicit vmcnt(0) drain before barrier
    short8 af[4], bfr[4];
#pragma unroll
    for (int r = 0; r < 4; ++r) {
      af[r]  = *reinterpret_cast<const short8*>(&As[(wr * 64 + r * 16 + l16) * 32 + lq * 8]);
      bfr[r] = *reinterpret_cast<const short8*>(&Bs[(wc * 64 + r * 16 + l16) * 32 + lq * 8]);
    }
#pragma unroll
    for (int r = 0; r < 4; ++r)
#pragma unroll
      for (int c = 0; c < 4; ++c)
        acc[r][c] = __builtin_amdgcn_mfma_f32_16x16x32_bf16(af[r], bfr[c], acc[r][c], 0, 0, 0);
    __syncthreads();
  }

#pragma unroll
  for (int r = 0; r < 4; ++r) {
    const int row0 = brow + wr * 64 + r * 16 + lq * 4;
#pragma unroll
    for (int c = 0; c < 4; ++c) {
      const int col = bcol + wc * 64 + c * 16 + l16;
#pragma unroll
      for (int i = 0; i < 4; ++i) {
        if constexpr (BF16_OUT)
          reinterpret_cast<uint16_t*>(Cout)[(size_t)(row0 + i) * N + col] = f2bf(acc[r][c][i]);
        else
          reinterpret_cast<float*>(Cout)[(size_t)(row0 + i) * N + col] = acc[r][c][i] + bias[col];
      }
    }
  }
}

// Flash attention, causal. qkv [MTOT][3072] bf16 (q|k|v), out [MTOT][1024] bf16.
// ROUND-15: exact revert to round-13 attn (best measured: 85.5us attn, 188.3 total).
// R14 split-KV removed (occupancy fell 31->25%, lost K-share, merge overhead: +3us
// attn, +11us total). Kept from the proven ladder: T1 XCD swizzle (FETCH 152->24.6MB),
// paired q-tiles (flat 33-iter blocks), A/B sequential (one sv[4] live), swapped QK^T,
// P-in-register via sigma-permuted V, uniform-diag branch, defer-max, exp2-fma,
// hw bf16 cvt, unrounded rsum, async-STAGE prefetch.
__global__ void __launch_bounds__(256, 3)
attn_fwd_k(const uint16_t* __restrict__ qkv, uint16_t* __restrict__ outb) {
  const int obid = blockIdx.x;
  const int bid = (obid & 7) * 128 + (obid >> 3);   // T1: contiguous 128-block chunk per XCD
  const int p = bid & 15;
  const int h = (bid >> 4) & 15;
  const int b = bid >> 8;
  const int qtA = p;
  const int qtB = 31 - p;
  const int tid = threadIdx.x;
  const int lane = tid & 63;
  const int w = tid >> 6;
  const int l16 = lane & 15;
  const int lq = lane >> 4;

  __shared__ uint16_t Ks[64 * 72];         // [token][d], stride 72
  __shared__ uint16_t Vt[64 * 72];         // [d][sigma-permuted token], stride 72

  // Q fragments for both q-tiles (row=l16, k=8*lq+j per 32-d chunk)
  short8 qaA0, qaA1, qaB0, qaB1;
  {
    const size_t baseA = ((size_t)(b * NSEQ + qtA * 64 + w * 16 + l16)) * QKV_LD + h * 64 + lq * 8;
    const size_t baseB = ((size_t)(b * NSEQ + qtB * 64 + w * 16 + l16)) * QKV_LD + h * 64 + lq * 8;
    qaA0 = *reinterpret_cast<const short8*>(qkv + baseA);
    qaA1 = *reinterpret_cast<const short8*>(qkv + baseA + 32);
    qaB0 = *reinterpret_cast<const short8*>(qkv + baseB);
    qaB1 = *reinterpret_cast<const short8*>(qkv + baseB + 32);
  }

  float mA = -1e30f, lA = 0.f, mB = -1e30f, lB = 0.f;
  f32x4 accA[4], accB[4];
  const f32x4 fzero = {0.f, 0.f, 0.f, 0.f};
#pragma unroll
  for (int i = 0; i < 4; ++i) { accA[i] = fzero; accB[i] = fzero; }

  // staging geometry: 512 chunks, chunk c -> token row c>>3, d-off (c&7)*8
  const int r0 = tid >> 3, d0 = (tid & 7) * 8;
  const int ka0 = r0 * 72 + d0;
  const int ka1 = (r0 + 32) * 72 + d0;
  const int lqt = (r0 >> 2) & 3;
  const int nc0 = r0 >> 4;
  const int m0 = d0 >> 3;
  const int jo = (nc0 & 1) * 4 + (r0 & 3);
  const int vcol0 = (((2 * lqt) ^ m0) * 8) + jo;        // token r0  -> pa0 chunk
  const int vcol1 = (((2 * lqt + 1) ^ m0) * 8) + jo;    // token r0+32 -> pa1 chunk

  const int ntiles = qtB + 1;
  short8 rk0, rk1, rv0, rv1;
  {
    const size_t g0 = ((size_t)(b * NSEQ + r0)) * QKV_LD + 1024 + h * 64 + d0;
    const size_t g1 = ((size_t)(b * NSEQ + r0 + 32)) * QKV_LD + 1024 + h * 64 + d0;
    rk0 = *reinterpret_cast<const short8*>(qkv + g0);
    rv0 = *reinterpret_cast<const short8*>(qkv + g0 + 1024);
    rk1 = *reinterpret_cast<const short8*>(qkv + g1);
    rv1 = *reinterpret_cast<const short8*>(qkv + g1 + 1024);
  }

#define SOFTMAX_PV(SV, M_I, L_I, ACC, DIAG)                                     \
  {                                                                             \
    float tmax_ = -3e38f;                                                       \
    if (DIAG) {                                                                 \
      _Pragma("unroll") for (int nc = 0; nc < 4; ++nc) {                        \
        _Pragma("unroll") for (int i = 0; i < 4; ++i) {                         \
          float v_ = SV[nc][i];                                                 \
          if ((nc * 16 + lq * 4 + i) > (w * 16 + l16)) v_ = -3e38f;             \
          SV[nc][i] = v_;                                                       \
          tmax_ = fmaxf(tmax_, v_);                                             \
        }                                                                       \
      }                                                                         \
    } else {                                                                    \
      _Pragma("unroll") for (int nc = 0; nc < 4; ++nc)                          \
        tmax_ = fmaxf(tmax_, fmaxf(fmaxf(SV[nc][0], SV[nc][1]),                 \
                                   fmaxf(SV[nc][2], SV[nc][3])));               \
    }                                                                           \
    tmax_ = fmaxf(tmax_, __shfl_xor(tmax_, 16, 64));                            \
    tmax_ = fmaxf(tmax_, __shfl_xor(tmax_, 32, 64));                            \
    if (!__all(tmax_ <= M_I + THR_RAW)) {                                       \
      const float mn_ = fmaxf(M_I, tmax_);                                      \
      const float alpha_ = EXP2((M_I - mn_) * C_SCL);                           \
      M_I = mn_;                                                                \
      L_I *= alpha_;                                                            \
      float ab_[4];                                                             \
      _Pragma("unroll") for (int i = 0; i < 4; ++i)                             \
        ab_[i] = __shfl(alpha_, lq * 4 + i, 64);                                \
      _Pragma("unroll") for (int d4 = 0; d4 < 4; ++d4)                          \
        _Pragma("unroll") for (int i = 0; i < 4; ++i)                           \
          ACC[d4][i] *= ab_[i];                                                 \
    }                                                                           \
    const float mc_ = M_I * C_SCL;                                              \
    float rsum_ = 0.f;                                                          \
    short8 pa0_, pa1_;                                                          \
    _Pragma("unroll") for (int nc = 0; nc < 4; ++nc) {                          \
      _Pragma("unroll") for (int i = 0; i < 4; ++i) {                           \
        float pv_ = EXP2(__builtin_fmaf(SV[nc][i], C_SCL, -mc_));               \
        rsum_ += pv_;                                                           \
        uint16_t ph_ = f2bf_hw(pv_);                                            \
        if (nc < 2) pa0_[nc * 4 + i] = (short)ph_;                              \
        else        pa1_[(nc - 2) * 4 + i] = (short)ph_;                        \
      }                                                                         \
    }                                                                           \
    rsum_ += __shfl_xor(rsum_, 16, 64);                                         \
    rsum_ += __shfl_xor(rsum_, 32, 64);                                         \
    L_I += rsum_;                                                               \
    _Pragma("unroll") for (int d4 = 0; d4 < 4; ++d4) {                          \
      const int drow_ = d4 * 16 + l16;                                          \
      const int xr_ = (drow_ >> 3) & 7;                                         \
      short8 vb0_ = *reinterpret_cast<const short8*>(&Vt[drow_ * 72 + (((2 * lq) ^ xr_) * 8)]); \
      short8 vb1_ = *reinterpret_cast<const short8*>(&Vt[drow_ * 72 + (((2 * lq + 1) ^ xr_) * 8)]); \
      ACC[d4] = __builtin_amdgcn_mfma_f32_16x16x32_bf16(pa0_, vb0_, ACC[d4], 0, 0, 0); \
      ACC[d4] = __builtin_amdgcn_mfma_f32_16x16x32_bf16(pa1_, vb1_, ACC[d4], 0, 0, 0); \
    }                                                                           \
  }

  for (int jt = 0; jt < ntiles; ++jt) {
    // --- commit staged regs to LDS (prev compute finished at loop-end barrier) ---
    *reinterpret_cast<short8*>(&Ks[ka0]) = rk0;
    *reinterpret_cast<short8*>(&Ks[ka1]) = rk1;
#pragma unroll
    for (int j = 0; j < 8; ++j) Vt[(d0 + j) * 72 + vcol0] = (uint16_t)rv0[j];
#pragma unroll
    for (int j = 0; j < 8; ++j) Vt[(d0 + j) * 72 + vcol1] = (uint16_t)rv1[j];
    // --- issue next tile's global loads; latency hides under this tile's compute ---
    if (jt + 1 < ntiles) {
      const size_t g0 = ((size_t)(b * NSEQ + (jt + 1) * 64 + r0)) * QKV_LD + 1024 + h * 64 + d0;
      const size_t g1 = ((size_t)(b * NSEQ + (jt + 1) * 64 + r0 + 32)) * QKV_LD + 1024 + h * 64 + d0;
      rk0 = *reinterpret_cast<const short8*>(qkv + g0);
      rv0 = *reinterpret_cast<const short8*>(qkv + g0 + 1024);
      rk1 = *reinterpret_cast<const short8*>(qkv + g1);
      rv1 = *reinterpret_cast<const short8*>(qkv + g1 + 1024);
    }
    __syncthreads();

    // --- tile B: S^T = K Q^T, softmax, PV ---
    {
      f32x4 sv[4];
#pragma unroll
      for (int nc = 0; nc < 4; ++nc) {
        short8 kb0 = *reinterpret_cast<const short8*>(&Ks[(nc * 16 + l16) * 72 + lq * 8]);
        short8 kb1 = *reinterpret_cast<const short8*>(&Ks[(nc * 16 + l16) * 72 + 32 + lq * 8]);
        f32x4 s = fzero;
        s = __builtin_amdgcn_mfma_f32_16x16x32_bf16(kb0, qaB0, s, 0, 0, 0);
        s = __builtin_amdgcn_mfma_f32_16x16x32_bf16(kb1, qaB1, s, 0, 0, 0);
        sv[nc] = s;
      }
      SOFTMAX_PV(sv, mB, lB, accB, jt == qtB);
    }

    // --- tile A (active while jt <= qtA) ---
    if (jt <= qtA) {
      f32x4 sv[4];
#pragma unroll
      for (int nc = 0; nc < 4; ++nc) {
        short8 kb0 = *reinterpret_cast<const short8*>(&Ks[(nc * 16 + l16) * 72 + lq * 8]);
        short8 kb1 = *reinterpret_cast<const short8*>(&Ks[(nc * 16 + l16) * 72 + 32 + lq * 8]);
        f32x4 s = fzero;
        s = __builtin_amdgcn_mfma_f32_16x16x32_bf16(kb0, qaA0, s, 0, 0, 0);
        s = __builtin_amdgcn_mfma_f32_16x16x32_bf16(kb1, qaA1, s, 0, 0, 0);
        sv[nc] = s;
      }
      SOFTMAX_PV(sv, mA, lA, accA, jt == qtA);
    }

    __syncthreads();   // protect Ks/Vt before next stage-commit
  }

  // epilogue: l for acc row q = lq*4 + i lives at lane l16 = q
  {
    float lb4[4];
#pragma unroll
    for (int i = 0; i < 4; ++i) lb4[i] = __shfl(lA, lq * 4 + i, 64);
    const size_t orow = (size_t)(b * NSEQ) + qtA * 64 + w * 16 + lq * 4;
#pragma unroll
    for (int d4 = 0; d4 < 4; ++d4)
#pragma unroll
      for (int i = 0; i < 4; ++i)
        outb[(orow + i) * (size_t)DMODEL + h * 64 + d4 * 16 + l16] = f2bf(accA[d4][i] / lb4[i]);
  }
  {
    float lb4[4];
#pragma unroll
    for (int i = 0; i < 4; ++i) lb4[i] = __shfl(lB, lq * 4 + i, 64);
    const size_t orow = (size_t)(b * NSEQ) + qtB * 64 + w * 16 + lq * 4;
#pragma unroll
    for (int d4 = 0; d4 < 4; ++d4)
#pragma unroll
      for (int i = 0; i < 4; ++i)
        outb[(orow + i) * (size_t)DMODEL + h * 64 + d4 * 16 + l16] = f2bf(accB[d4][i] / lb4[i]);
  }
}

extern "C" void kernel_launch(void* const* d_in, const int* in_sizes, int n_in,
                              void* d_out, int out_size, void* d_ws, size_t ws_size,
                              hipStream_t stream) {
  const float* x      = (const float*)d_in[0];
  const float* w_attn = (const float*)d_in[1];
  const float* w_proj = (const float*)d_in[2];
  const float* b_proj = (const float*)d_in[3];

  uint16_t* xb    = (uint16_t*)d_ws;                    // [8192][1024]
  uint16_t* wat   = xb   + (size_t)MTOT * DMODEL;       // [3072][1024] (w_attn^T)
  uint16_t* wpt   = wat  + (size_t)3072 * 1024;         // [1024][1024] (w_proj^T)
  uint16_t* qkvb  = wpt  + (size_t)1024 * 1024;         // [8192][3072]
  uint16_t* attnb = qkvb + (size_t)MTOT * QKV_LD;       // [8192][1024]

  cast_f32_bf16_k<<<2048, 256, 0, stream>>>(x, xb, MTOT * DMODEL);
  transpose_cast_k<<<dim3(3072 / 32, 1024 / 32), 256, 0, stream>>>(w_attn, wat, 1024, 3072);
  transpose_cast_k<<<dim3(1024 / 32, 1024 / 32), 256, 0, stream>>>(w_proj, wpt, 1024, 1024);

  gemm_bt_k<true><<<dim3(3072 / 128, MTOT / 128), 256, 0, stream>>>(
      xb, wat, qkvb, nullptr, MTOT, 3072, 1024);

  attn_fwd_k<<<BQ * NHEAD * 16, 256, 0, stream>>>(qkvb, attnb);

  gemm_bt_k<false><<<dim3(1024 / 128, MTOT / 128), 256, 0, stream>>>(
      attnb, wpt, d_out, b_proj, MTOT, 1024, 1024);
}

// Round 16
// 187.668 us; speedup vs baseline: 1.0622x; 1.0033x over previous
//
#include <hip/hip_runtime.h>
#include <hip/hip_bf16.h>
#include <stdint.h>

typedef short short8 __attribute__((ext_vector_type(8)));
typedef float f32x4 __attribute__((ext_vector_type(4)));

#define BQ 4
#define NSEQ 2048
#define DMODEL 1024
#define NHEAD 16
#define HDIM 64
#define MTOT 8192          // BQ*NSEQ
#define QKV_LD 3072

#if __has_builtin(__builtin_amdgcn_exp2f)
#define EXP2(x) __builtin_amdgcn_exp2f(x)
#else
#define EXP2(x) exp2f(x)
#endif
#define C_SCL 0.18033688f   // 0.125 * log2(e)
#define THR_RAW 16.635532f  // 3.0 / C_SCL : defer-max threshold (P bounded by 2^3)

__device__ __forceinline__ uint16_t f2bf(float f) {
  uint32_t u = __builtin_bit_cast(uint32_t, f);
  uint32_t r = (u + 0x7FFFu + ((u >> 16) & 1u)) >> 16;
  return (uint16_t)r;
}
// hardware RNE convert (v_cvt_pk_bf16_f32 after compiler fusion)
__device__ __forceinline__ uint16_t f2bf_hw(float f) {
  __hip_bfloat16 h = __float2bfloat16(f);
  return __builtin_bit_cast(uint16_t, h);
}

// ROUND-16: single prep kernel = cast(x) + transpose(w_attn) + transpose(w_proj).
// Three BW-bound independent phases, block-range dispatch: one launch instead of
// three -> saves 2 launch/ramp overheads and lets the phases overlap on-device.
__global__ void prep_k(const float* __restrict__ x, uint16_t* __restrict__ xb,
                       const float* __restrict__ w_attn, uint16_t* __restrict__ wat,
                       const float* __restrict__ w_proj, uint16_t* __restrict__ wpt) {
  __shared__ float tile[32][33];
  const int bid = blockIdx.x;
  if (bid < 2048) {
    // cast x [8192*1024] f32 -> bf16
    int idx = (bid * 256 + threadIdx.x) * 4;
    const int stride = 2048 * 256 * 4;
    for (int i = idx; i < MTOT * DMODEL; i += stride) {
      float4 v = *reinterpret_cast<const float4*>(x + i);
      ushort4 o;
      o.x = f2bf(v.x); o.y = f2bf(v.y); o.z = f2bf(v.z); o.w = f2bf(v.w);
      *reinterpret_cast<ushort4*>(xb + i) = o;
    }
    return;
  }
  // transpose+cast: in [K=1024][N] f32 -> out [N][K] bf16
  const float* in; uint16_t* out; int N, t;
  if (bid < 2048 + 3072) { in = w_attn; out = wat; N = 3072; t = bid - 2048; }
  else                   { in = w_proj; out = wpt; N = 1024; t = bid - 5120; }
  const int K = 1024;
  const int nb = N / 32;
  const int n0 = (t % nb) * 32;
  const int k0 = (t / nb) * 32;
  const int tx = threadIdx.x & 31;
  const int ty = threadIdx.x >> 5;
#pragma unroll
  for (int r = 0; r < 4; ++r)
    tile[ty + r * 8][tx] = in[(size_t)(k0 + ty + r * 8) * N + n0 + tx];
  __syncthreads();
#pragma unroll
  for (int r = 0; r < 4; ++r)
    out[(size_t)(n0 + ty + r * 8) * K + k0 + tx] = f2bf(tile[tx][ty + r * 8]);
}

// C[M,N] = A[M,K] @ BT[N,K]^T ; A,BT bf16 row-major. 128x128 tile, BK=32.
// Staging via global_load_lds width=16 (m97 structure). At its measured ceiling
// (m99-m141: all source-level pipelining lands 839-890 TF on this structure).
template <bool BF16_OUT>
__global__ void __launch_bounds__(256, 3)
gemm_bt_k(const uint16_t* __restrict__ A, const uint16_t* __restrict__ BT,
          void* __restrict__ Cout, const float* __restrict__ bias,
          int M, int N, int K) {
  __shared__ uint16_t As[128 * 32];
  __shared__ uint16_t Bs[128 * 32];
  const int tid = threadIdx.x;
  const int lane = tid & 63;
  const int wave = tid >> 6;
  const int wr = wave >> 1, wc = wave & 1;   // wave -> 64x64 quadrant
  const int brow = blockIdx.y * 128;
  const int bcol = blockIdx.x * 128;
  const int l16 = lane & 15;
  const int lq = lane >> 4;

  f32x4 acc[4][4];
  const f32x4 fzero = {0.f, 0.f, 0.f, 0.f};
#pragma unroll
  for (int i = 0; i < 4; ++i)
#pragma unroll
    for (int j = 0; j < 4; ++j) acc[i][j] = fzero;

  // staging: 512 16B-chunks per tile; chunk c -> row c>>2, k-off (c&3)*8; LDS linear at c*8 elems
  const int ca = tid, cb = tid + 256;
  const size_t ga0 = (size_t)(brow + (ca >> 2)) * K + (ca & 3) * 8;
  const size_t ga1 = (size_t)(brow + (cb >> 2)) * K + (cb & 3) * 8;
  const size_t gb0 = (size_t)(bcol + (ca >> 2)) * K + (ca & 3) * 8;
  const size_t gb1 = (size_t)(bcol + (cb >> 2)) * K + (cb & 3) * 8;

  for (int kt = 0; kt < K; kt += 32) {
    __builtin_amdgcn_global_load_lds(
        (const __attribute__((address_space(1))) void*)(A + ga0 + kt),
        (__attribute__((address_space(3))) void*)&As[ca * 8], 16, 0, 0);
    __builtin_amdgcn_global_load_lds(
        (const __attribute__((address_space(1))) void*)(A + ga1 + kt),
        (__attribute__((address_space(3))) void*)&As[cb * 8], 16, 0, 0);
    __builtin_amdgcn_global_load_lds(
        (const __attribute__((address_space(1))) void*)(BT + gb0 + kt),
        (__attribute__((address_space(3))) void*)&Bs[ca * 8], 16, 0, 0);
    __builtin_amdgcn_global_load_lds(
        (const __attribute__((address_space(1))) void*)(BT + gb1 + kt),
        (__attribute__((address_space(3))) void*)&Bs[cb * 8], 16, 0, 0);
    __syncthreads();   // implicit vmcnt(0) drain before barrier
    short8 af[4], bfr[4];
#pragma unroll
    for (int r = 0; r < 4; ++r) {
      af[r]  = *reinterpret_cast<const short8*>(&As[(wr * 64 + r * 16 + l16) * 32 + lq * 8]);
      bfr[r] = *reinterpret_cast<const short8*>(&Bs[(wc * 64 + r * 16 + l16) * 32 + lq * 8]);
    }
#pragma unroll
    for (int r = 0; r < 4; ++r)
#pragma unroll
      for (int c = 0; c < 4; ++c)
        acc[r][c] = __builtin_amdgcn_mfma_f32_16x16x32_bf16(af[r], bfr[c], acc[r][c], 0, 0, 0);
    __syncthreads();
  }

#pragma unroll
  for (int r = 0; r < 4; ++r) {
    const int row0 = brow + wr * 64 + r * 16 + lq * 4;
#pragma unroll
    for (int c = 0; c < 4; ++c) {
      const int col = bcol + wc * 64 + c * 16 + l16;
#pragma unroll
      for (int i = 0; i < 4; ++i) {
        if constexpr (BF16_OUT)
          reinterpret_cast<uint16_t*>(Cout)[(size_t)(row0 + i) * N + col] = f2bf(acc[r][c][i]);
        else
          reinterpret_cast<float*>(Cout)[(size_t)(row0 + i) * N + col] = acc[r][c][i] + bias[col];
      }
    }
  }
}

// Flash attention, causal. qkv [MTOT][3072] bf16 (q|k|v), out [MTOT][1024] bf16.
// Round-13 structure (best measured: 85.5-85.8us attn): T1 XCD swizzle (FETCH
// 152->24.6MB), paired q-tiles (flat 33-iter blocks), A/B sequential (one sv[4]
// live), swapped QK^T, P-in-register via sigma-permuted V, uniform-diag branch,
// defer-max, exp2-fma, hw bf16 cvt, unrounded rsum, async-STAGE prefetch.
__global__ void __launch_bounds__(256, 3)
attn_fwd_k(const uint16_t* __restrict__ qkv, uint16_t* __restrict__ outb) {
  const int obid = blockIdx.x;
  const int bid = (obid & 7) * 128 + (obid >> 3);   // T1: contiguous 128-block chunk per XCD
  const int p = bid & 15;
  const int h = (bid >> 4) & 15;
  const int b = bid >> 8;
  const int qtA = p;
  const int qtB = 31 - p;
  const int tid = threadIdx.x;
  const int lane = tid & 63;
  const int w = tid >> 6;
  const int l16 = lane & 15;
  const int lq = lane >> 4;

  __shared__ uint16_t Ks[64 * 72];         // [token][d], stride 72
  __shared__ uint16_t Vt[64 * 72];         // [d][sigma-permuted token], stride 72

  // Q fragments for both q-tiles (row=l16, k=8*lq+j per 32-d chunk)
  short8 qaA0, qaA1, qaB0, qaB1;
  {
    const size_t baseA = ((size_t)(b * NSEQ + qtA * 64 + w * 16 + l16)) * QKV_LD + h * 64 + lq * 8;
    const size_t baseB = ((size_t)(b * NSEQ + qtB * 64 + w * 16 + l16)) * QKV_LD + h * 64 + lq * 8;
    qaA0 = *reinterpret_cast<const short8*>(qkv + baseA);
    qaA1 = *reinterpret_cast<const short8*>(qkv + baseA + 32);
    qaB0 = *reinterpret_cast<const short8*>(qkv + baseB);
    qaB1 = *reinterpret_cast<const short8*>(qkv + baseB + 32);
  }

  float mA = -1e30f, lA = 0.f, mB = -1e30f, lB = 0.f;
  f32x4 accA[4], accB[4];
  const f32x4 fzero = {0.f, 0.f, 0.f, 0.f};
#pragma unroll
  for (int i = 0; i < 4; ++i) { accA[i] = fzero; accB[i] = fzero; }

  // staging geometry: 512 chunks, chunk c -> token row c>>3, d-off (c&7)*8
  const int r0 = tid >> 3, d0 = (tid & 7) * 8;
  const int ka0 = r0 * 72 + d0;
  const int ka1 = (r0 + 32) * 72 + d0;
  const int lqt = (r0 >> 2) & 3;
  const int nc0 = r0 >> 4;
  const int m0 = d0 >> 3;
  const int jo = (nc0 & 1) * 4 + (r0 & 3);
  const int vcol0 = (((2 * lqt) ^ m0) * 8) + jo;        // token r0  -> pa0 chunk
  const int vcol1 = (((2 * lqt + 1) ^ m0) * 8) + jo;    // token r0+32 -> pa1 chunk

  const int ntiles = qtB + 1;
  short8 rk0, rk1, rv0, rv1;
  {
    const size_t g0 = ((size_t)(b * NSEQ + r0)) * QKV_LD + 1024 + h * 64 + d0;
    const size_t g1 = ((size_t)(b * NSEQ + r0 + 32)) * QKV_LD + 1024 + h * 64 + d0;
    rk0 = *reinterpret_cast<const short8*>(qkv + g0);
    rv0 = *reinterpret_cast<const short8*>(qkv + g0 + 1024);
    rk1 = *reinterpret_cast<const short8*>(qkv + g1);
    rv1 = *reinterpret_cast<const short8*>(qkv + g1 + 1024);
  }

#define SOFTMAX_PV(SV, M_I, L_I, ACC, DIAG)                                     \
  {                                                                             \
    float tmax_ = -3e38f;                                                       \
    if (DIAG) {                                                                 \
      _Pragma("unroll") for (int nc = 0; nc < 4; ++nc) {                        \
        _Pragma("unroll") for (int i = 0; i < 4; ++i) {                         \
          float v_ = SV[nc][i];                                                 \
          if ((nc * 16 + lq * 4 + i) > (w * 16 + l16)) v_ = -3e38f;             \
          SV[nc][i] = v_;                                                       \
          tmax_ = fmaxf(tmax_, v_);                                             \
        }                                                                       \
      }                                                                         \
    } else {                                                                    \
      _Pragma("unroll") for (int nc = 0; nc < 4; ++nc)                          \
        tmax_ = fmaxf(tmax_, fmaxf(fmaxf(SV[nc][0], SV[nc][1]),                 \
                                   fmaxf(SV[nc][2], SV[nc][3])));               \
    }                                                                           \
    tmax_ = fmaxf(tmax_, __shfl_xor(tmax_, 16, 64));                            \
    tmax_ = fmaxf(tmax_, __shfl_xor(tmax_, 32, 64));                            \
    if (!__all(tmax_ <= M_I + THR_RAW)) {                                       \
      const float mn_ = fmaxf(M_I, tmax_);                                      \
      const float alpha_ = EXP2((M_I - mn_) * C_SCL);                           \
      M_I = mn_;                                                                \
      L_I *= alpha_;                                                            \
      float ab_[4];                                                             \
      _Pragma("unroll") for (int i = 0; i < 4; ++i)                             \
        ab_[i] = __shfl(alpha_, lq * 4 + i, 64);                                \
      _Pragma("unroll") for (int d4 = 0; d4 < 4; ++d4)                          \
        _Pragma("unroll") for (int i = 0; i < 4; ++i)                           \
          ACC[d4][i] *= ab_[i];                                                 \
    }                                                                           \
    const float mc_ = M_I * C_SCL;                                              \
    float rsum_ = 0.f;                                                          \
    short8 pa0_, pa1_;                                                          \
    _Pragma("unroll") for (int nc = 0; nc < 4; ++nc) {                          \
      _Pragma("unroll") for (int i = 0; i < 4; ++i) {                           \
        float pv_ = EXP2(__builtin_fmaf(SV[nc][i], C_SCL, -mc_));               \
        rsum_ += pv_;                                                           \
        uint16_t ph_ = f2bf_hw(pv_);                                            \
        if (nc < 2) pa0_[nc * 4 + i] = (short)ph_;                              \
        else        pa1_[(nc - 2) * 4 + i] = (short)ph_;                        \
      }                                                                         \
    }                                                                           \
    rsum_ += __shfl_xor(rsum_, 16, 64);                                         \
    rsum_ += __shfl_xor(rsum_, 32, 64);                                         \
    L_I += rsum_;                                                               \
    _Pragma("unroll") for (int d4 = 0; d4 < 4; ++d4) {                          \
      const int drow_ = d4 * 16 + l16;                                          \
      const int xr_ = (drow_ >> 3) & 7;                                         \
      short8 vb0_ = *reinterpret_cast<const short8*>(&Vt[drow_ * 72 + (((2 * lq) ^ xr_) * 8)]); \
      short8 vb1_ = *reinterpret_cast<const short8*>(&Vt[drow_ * 72 + (((2 * lq + 1) ^ xr_) * 8)]); \
      ACC[d4] = __builtin_amdgcn_mfma_f32_16x16x32_bf16(pa0_, vb0_, ACC[d4], 0, 0, 0); \
      ACC[d4] = __builtin_amdgcn_mfma_f32_16x16x32_bf16(pa1_, vb1_, ACC[d4], 0, 0, 0); \
    }                                                                           \
  }

  for (int jt = 0; jt < ntiles; ++jt) {
    // --- commit staged regs to LDS (prev compute finished at loop-end barrier) ---
    *reinterpret_cast<short8*>(&Ks[ka0]) = rk0;
    *reinterpret_cast<short8*>(&Ks[ka1]) = rk1;
#pragma unroll
    for (int j = 0; j < 8; ++j) Vt[(d0 + j) * 72 + vcol0] = (uint16_t)rv0[j];
#pragma unroll
    for (int j = 0; j < 8; ++j) Vt[(d0 + j) * 72 + vcol1] = (uint16_t)rv1[j];
    // --- issue next tile's global loads; latency hides under this tile's compute ---
    if (jt + 1 < ntiles) {
      const size_t g0 = ((size_t)(b * NSEQ + (jt + 1) * 64 + r0)) * QKV_LD + 1024 + h * 64 + d0;
      const size_t g1 = ((size_t)(b * NSEQ + (jt + 1) * 64 + r0 + 32)) * QKV_LD + 1024 + h * 64 + d0;
      rk0 = *reinterpret_cast<const short8*>(qkv + g0);
      rv0 = *reinterpret_cast<const short8*>(qkv + g0 + 1024);
      rk1 = *reinterpret_cast<const short8*>(qkv + g1);
      rv1 = *reinterpret_cast<const short8*>(qkv + g1 + 1024);
    }
    __syncthreads();

    // --- tile B: S^T = K Q^T, softmax, PV ---
    {
      f32x4 sv[4];
#pragma unroll
      for (int nc = 0; nc < 4; ++nc) {
        short8 kb0 = *reinterpret_cast<const short8*>(&Ks[(nc * 16 + l16) * 72 + lq * 8]);
        short8 kb1 = *reinterpret_cast<const short8*>(&Ks[(nc * 16 + l16) * 72 + 32 + lq * 8]);
        f32x4 s = fzero;
        s = __builtin_amdgcn_mfma_f32_16x16x32_bf16(kb0, qaB0, s, 0, 0, 0);
        s = __builtin_amdgcn_mfma_f32_16x16x32_bf16(kb1, qaB1, s, 0, 0, 0);
        sv[nc] = s;
      }
      SOFTMAX_PV(sv, mB, lB, accB, jt == qtB);
    }

    // --- tile A (active while jt <= qtA) ---
    if (jt <= qtA) {
      f32x4 sv[4];
#pragma unroll
      for (int nc = 0; nc < 4; ++nc) {
        short8 kb0 = *reinterpret_cast<const short8*>(&Ks[(nc * 16 + l16) * 72 + lq * 8]);
        short8 kb1 = *reinterpret_cast<const short8*>(&Ks[(nc * 16 + l16) * 72 + 32 + lq * 8]);
        f32x4 s = fzero;
        s = __builtin_amdgcn_mfma_f32_16x16x32_bf16(kb0, qaA0, s, 0, 0, 0);
        s = __builtin_amdgcn_mfma_f32_16x16x32_bf16(kb1, qaA1, s, 0, 0, 0);
        sv[nc] = s;
      }
      SOFTMAX_PV(sv, mA, lA, accA, jt == qtA);
    }

    __syncthreads();   // protect Ks/Vt before next stage-commit
  }

  // epilogue: l for acc row q = lq*4 + i lives at lane l16 = q
  {
    float lb4[4];
#pragma unroll
    for (int i = 0; i < 4; ++i) lb4[i] = __shfl(lA, lq * 4 + i, 64);
    const size_t orow = (size_t)(b * NSEQ) + qtA * 64 + w * 16 + lq * 4;
#pragma unroll
    for (int d4 = 0; d4 < 4; ++d4)
#pragma unroll
      for (int i = 0; i < 4; ++i)
        outb[(orow + i) * (size_t)DMODEL + h * 64 + d4 * 16 + l16] = f2bf_hw(accA[d4][i] / lb4[i]);
  }
  {
    float lb4[4];
#pragma unroll
    for (int i = 0; i < 4; ++i) lb4[i] = __shfl(lB, lq * 4 + i, 64);
    const size_t orow = (size_t)(b * NSEQ) + qtB * 64 + w * 16 + lq * 4;
#pragma unroll
    for (int d4 = 0; d4 < 4; ++d4)
#pragma unroll
      for (int i = 0; i < 4; ++i)
        outb[(orow + i) * (size_t)DMODEL + h * 64 + d4 * 16 + l16] = f2bf_hw(accB[d4][i] / lb4[i]);
  }
}

extern "C" void kernel_launch(void* const* d_in, const int* in_sizes, int n_in,
                              void* d_out, int out_size, void* d_ws, size_t ws_size,
                              hipStream_t stream) {
  const float* x      = (const float*)d_in[0];
  const float* w_attn = (const float*)d_in[1];
  const float* w_proj = (const float*)d_in[2];
  const float* b_proj = (const float*)d_in[3];

  uint16_t* xb    = (uint16_t*)d_ws;                    // [8192][1024]
  uint16_t* wat   = xb   + (size_t)MTOT * DMODEL;       // [3072][1024] (w_attn^T)
  uint16_t* wpt   = wat  + (size_t)3072 * 1024;         // [1024][1024] (w_proj^T)
  uint16_t* qkvb  = wpt  + (size_t)1024 * 1024;         // [8192][3072]
  uint16_t* attnb = qkvb + (size_t)MTOT * QKV_LD;       // [8192][1024]

  prep_k<<<2048 + 3072 + 1024, 256, 0, stream>>>(x, xb, w_attn, wat, w_proj, wpt);

  gemm_bt_k<true><<<dim3(3072 / 128, MTOT / 128), 256, 0, stream>>>(
      xb, wat, qkvb, nullptr, MTOT, 3072, 1024);

  attn_fwd_k<<<BQ * NHEAD * 16, 256, 0, stream>>>(qkvb, attnb);

  gemm_bt_k<false><<<dim3(1024 / 128, MTOT / 128), 256, 0, stream>>>(
      attnb, wpt, d_out, b_proj, MTOT, 1024, 1024);
}

// Round 17
// 180.038 us; speedup vs baseline: 1.1072x; 1.0424x over previous
//
#include <hip/hip_runtime.h>
#include <hip/hip_bf16.h>
#include <stdint.h>

typedef short short8 __attribute__((ext_vector_type(8)));
typedef float f32x4 __attribute__((ext_vector_type(4)));

#define BQ 4
#define NSEQ 2048
#define DMODEL 1024
#define NHEAD 16
#define HDIM 64
#define MTOT 8192          // BQ*NSEQ
#define QKV_LD 3072

#if __has_builtin(__builtin_amdgcn_exp2f)
#define EXP2(x) __builtin_amdgcn_exp2f(x)
#else
#define EXP2(x) exp2f(x)
#endif
#define C_SCL 0.18033688f   // 0.125 * log2(e)
#define THR_RAW 16.635532f  // 3.0 / C_SCL : defer-max threshold (P bounded by 2^3)

__device__ __forceinline__ uint16_t f2bf(float f) {
  uint32_t u = __builtin_bit_cast(uint32_t, f);
  uint32_t r = (u + 0x7FFFu + ((u >> 16) & 1u)) >> 16;
  return (uint16_t)r;
}
// hardware RNE convert (v_cvt_pk_bf16_f32 after compiler fusion)
__device__ __forceinline__ uint16_t f2bf_hw(float f) {
  __hip_bfloat16 h = __float2bfloat16(f);
  return __builtin_bit_cast(uint16_t, h);
}

// Single prep kernel = cast(x) + transpose(w_attn) + transpose(w_proj).
__global__ void prep_k(const float* __restrict__ x, uint16_t* __restrict__ xb,
                       const float* __restrict__ w_attn, uint16_t* __restrict__ wat,
                       const float* __restrict__ w_proj, uint16_t* __restrict__ wpt) {
  __shared__ float tile[32][33];
  const int bid = blockIdx.x;
  if (bid < 2048) {
    // cast x [8192*1024] f32 -> bf16
    int idx = (bid * 256 + threadIdx.x) * 4;
    const int stride = 2048 * 256 * 4;
    for (int i = idx; i < MTOT * DMODEL; i += stride) {
      float4 v = *reinterpret_cast<const float4*>(x + i);
      ushort4 o;
      o.x = f2bf(v.x); o.y = f2bf(v.y); o.z = f2bf(v.z); o.w = f2bf(v.w);
      *reinterpret_cast<ushort4*>(xb + i) = o;
    }
    return;
  }
  // transpose+cast: in [K=1024][N] f32 -> out [N][K] bf16
  const float* in; uint16_t* out; int N, t;
  if (bid < 2048 + 3072) { in = w_attn; out = wat; N = 3072; t = bid - 2048; }
  else                   { in = w_proj; out = wpt; N = 1024; t = bid - 5120; }
  const int K = 1024;
  const int nb = N / 32;
  const int n0 = (t % nb) * 32;
  const int k0 = (t / nb) * 32;
  const int tx = threadIdx.x & 31;
  const int ty = threadIdx.x >> 5;
#pragma unroll
  for (int r = 0; r < 4; ++r)
    tile[ty + r * 8][tx] = in[(size_t)(k0 + ty + r * 8) * N + n0 + tx];
  __syncthreads();
#pragma unroll
  for (int r = 0; r < 4; ++r)
    out[(size_t)(n0 + ty + r * 8) * K + k0 + tx] = f2bf(tile[tx][ty + r * 8]);
}

// C[M,N] = A[M,K] @ BT[N,K]^T ; A,BT bf16 row-major. 128x128 tile.
// ROUND-17: BK=32 -> BK=64. Halves the K-iterations (32->16) so the structure's
// defining stall (vmcnt(0) drain before each barrier, ~20% of time per m97 asm
// analysis) amortizes over 2x MFMA work. m132's BK=128 failure was LDS-occupancy
// (64KB -> 2 blocks/CU); BK=64 keeps 32KB -> 3 blocks/CU intact.
// Banking: stride-128B rows would put each l16-group's b128 reads on 4 banks
// (16-way). Fix per m173 (global_load_lds writes linearly, can't swizzle dest):
// PRE-SWIZZLE THE GLOBAL SOURCE — row r's LDS slot s holds global k-chunk
// s ^ (r&7); reader uses slot (kk*4+lq) ^ (l16&7) -> 8 distinct XOR values x 4
// dwords = all 32 banks, 2 lanes/bank (minimum phases, conflict-free).
template <bool BF16_OUT>
__global__ void __launch_bounds__(256, 3)
gemm_bt_k(const uint16_t* __restrict__ A, const uint16_t* __restrict__ BT,
          void* __restrict__ Cout, const float* __restrict__ bias,
          int M, int N, int K) {
  __shared__ uint16_t As[128 * 64];
  __shared__ uint16_t Bs[128 * 64];
  const int tid = threadIdx.x;
  const int lane = tid & 63;
  const int wave = tid >> 6;
  const int wr = wave >> 1, wc = wave & 1;   // wave -> 64x64 quadrant
  const int brow = blockIdx.y * 128;
  const int bcol = blockIdx.x * 128;
  const int l16 = lane & 15;
  const int lq = lane >> 4;

  f32x4 acc[4][4];
  const f32x4 fzero = {0.f, 0.f, 0.f, 0.f};
#pragma unroll
  for (int i = 0; i < 4; ++i)
#pragma unroll
    for (int j = 0; j < 4; ++j) acc[i][j] = fzero;

  // staging: 1024 16B-chunks per 128x64 tile; chunk c -> row c>>3, slot c&7;
  // slot holds global k-chunk (c&7) ^ (row&7). LDS linear at c*8 elems.
  size_t gA0, gA1, gA2, gA3, gB0, gB1, gB2, gB3;
  int ls0, ls1, ls2, ls3;
  {
    int c0 = tid, c1 = tid + 256, c2 = tid + 512, c3 = tid + 768;
    int r0 = c0 >> 3, r1 = c1 >> 3, r2 = c2 >> 3, r3 = c3 >> 3;
    int k0 = (c0 & 7) ^ (r0 & 7), k1 = (c1 & 7) ^ (r1 & 7);
    int k2 = (c2 & 7) ^ (r2 & 7), k3 = (c3 & 7) ^ (r3 & 7);
    gA0 = (size_t)(brow + r0) * K + k0 * 8;  gB0 = (size_t)(bcol + r0) * K + k0 * 8;
    gA1 = (size_t)(brow + r1) * K + k1 * 8;  gB1 = (size_t)(bcol + r1) * K + k1 * 8;
    gA2 = (size_t)(brow + r2) * K + k2 * 8;  gB2 = (size_t)(bcol + r2) * K + k2 * 8;
    gA3 = (size_t)(brow + r3) * K + k3 * 8;  gB3 = (size_t)(bcol + r3) * K + k3 * 8;
    ls0 = c0 * 8; ls1 = c1 * 8; ls2 = c2 * 8; ls3 = c3 * 8;
  }

#define GLD(PTR, OFF, LDSARR, LS)                                               \
  __builtin_amdgcn_global_load_lds(                                             \
      (const __attribute__((address_space(1))) void*)((PTR) + (OFF)),           \
      (__attribute__((address_space(3))) void*)&LDSARR[LS], 16, 0, 0)

  for (int kt = 0; kt < K; kt += 64) {
    GLD(A, gA0 + kt, As, ls0);
    GLD(A, gA1 + kt, As, ls1);
    GLD(A, gA2 + kt, As, ls2);
    GLD(A, gA3 + kt, As, ls3);
    GLD(BT, gB0 + kt, Bs, ls0);
    GLD(BT, gB1 + kt, Bs, ls1);
    GLD(BT, gB2 + kt, Bs, ls2);
    GLD(BT, gB3 + kt, Bs, ls3);
    __syncthreads();   // implicit vmcnt(0) drain before barrier (once per 64 K now)
#pragma unroll
    for (int kk = 0; kk < 2; ++kk) {
      short8 af[4], bfr[4];
#pragma unroll
      for (int r = 0; r < 4; ++r) {
        const int rowA = wr * 64 + r * 16 + l16;
        const int rowB = wc * 64 + r * 16 + l16;
        const int slot = (kk * 4 + lq) ^ (l16 & 7);   // (row&7) == (l16&7)
        af[r]  = *reinterpret_cast<const short8*>(&As[rowA * 64 + slot * 8]);
        bfr[r] = *reinterpret_cast<const short8*>(&Bs[rowB * 64 + slot * 8]);
      }
#pragma unroll
      for (int r = 0; r < 4; ++r)
#pragma unroll
        for (int c = 0; c < 4; ++c)
          acc[r][c] = __builtin_amdgcn_mfma_f32_16x16x32_bf16(af[r], bfr[c], acc[r][c], 0, 0, 0);
    }
    __syncthreads();
  }
#undef GLD

#pragma unroll
  for (int r = 0; r < 4; ++r) {
    const int row0 = brow + wr * 64 + r * 16 + lq * 4;
#pragma unroll
    for (int c = 0; c < 4; ++c) {
      const int col = bcol + wc * 64 + c * 16 + l16;
#pragma unroll
      for (int i = 0; i < 4; ++i) {
        if constexpr (BF16_OUT)
          reinterpret_cast<uint16_t*>(Cout)[(size_t)(row0 + i) * N + col] = f2bf_hw(acc[r][c][i]);
        else
          reinterpret_cast<float*>(Cout)[(size_t)(row0 + i) * N + col] = acc[r][c][i] + bias[col];
      }
    }
  }
}

// Flash attention, causal. qkv [MTOT][3072] bf16 (q|k|v), out [MTOT][1024] bf16.
// Round-13 structure (best measured: 85.5-85.8us attn): T1 XCD swizzle (FETCH
// 152->24.6MB), paired q-tiles (flat 33-iter blocks), A/B sequential (one sv[4]
// live), swapped QK^T, P-in-register via sigma-permuted V, uniform-diag branch,
// defer-max, exp2-fma, hw bf16 cvt, unrounded rsum, async-STAGE prefetch.
__global__ void __launch_bounds__(256, 3)
attn_fwd_k(const uint16_t* __restrict__ qkv, uint16_t* __restrict__ outb) {
  const int obid = blockIdx.x;
  const int bid = (obid & 7) * 128 + (obid >> 3);   // T1: contiguous 128-block chunk per XCD
  const int p = bid & 15;
  const int h = (bid >> 4) & 15;
  const int b = bid >> 8;
  const int qtA = p;
  const int qtB = 31 - p;
  const int tid = threadIdx.x;
  const int lane = tid & 63;
  const int w = tid >> 6;
  const int l16 = lane & 15;
  const int lq = lane >> 4;

  __shared__ uint16_t Ks[64 * 72];         // [token][d], stride 72
  __shared__ uint16_t Vt[64 * 72];         // [d][sigma-permuted token], stride 72

  // Q fragments for both q-tiles (row=l16, k=8*lq+j per 32-d chunk)
  short8 qaA0, qaA1, qaB0, qaB1;
  {
    const size_t baseA = ((size_t)(b * NSEQ + qtA * 64 + w * 16 + l16)) * QKV_LD + h * 64 + lq * 8;
    const size_t baseB = ((size_t)(b * NSEQ + qtB * 64 + w * 16 + l16)) * QKV_LD + h * 64 + lq * 8;
    qaA0 = *reinterpret_cast<const short8*>(qkv + baseA);
    qaA1 = *reinterpret_cast<const short8*>(qkv + baseA + 32);
    qaB0 = *reinterpret_cast<const short8*>(qkv + baseB);
    qaB1 = *reinterpret_cast<const short8*>(qkv + baseB + 32);
  }

  float mA = -1e30f, lA = 0.f, mB = -1e30f, lB = 0.f;
  f32x4 accA[4], accB[4];
  const f32x4 fzero = {0.f, 0.f, 0.f, 0.f};
#pragma unroll
  for (int i = 0; i < 4; ++i) { accA[i] = fzero; accB[i] = fzero; }

  // staging geometry: 512 chunks, chunk c -> token row c>>3, d-off (c&7)*8
  const int r0 = tid >> 3, d0 = (tid & 7) * 8;
  const int ka0 = r0 * 72 + d0;
  const int ka1 = (r0 + 32) * 72 + d0;
  const int lqt = (r0 >> 2) & 3;
  const int nc0 = r0 >> 4;
  const int m0 = d0 >> 3;
  const int jo = (nc0 & 1) * 4 + (r0 & 3);
  const int vcol0 = (((2 * lqt) ^ m0) * 8) + jo;        // token r0  -> pa0 chunk
  const int vcol1 = (((2 * lqt + 1) ^ m0) * 8) + jo;    // token r0+32 -> pa1 chunk

  const int ntiles = qtB + 1;
  short8 rk0, rk1, rv0, rv1;
  {
    const size_t g0 = ((size_t)(b * NSEQ + r0)) * QKV_LD + 1024 + h * 64 + d0;
    const size_t g1 = ((size_t)(b * NSEQ + r0 + 32)) * QKV_LD + 1024 + h * 64 + d0;
    rk0 = *reinterpret_cast<const short8*>(qkv + g0);
    rv0 = *reinterpret_cast<const short8*>(qkv + g0 + 1024);
    rk1 = *reinterpret_cast<const short8*>(qkv + g1);
    rv1 = *reinterpret_cast<const short8*>(qkv + g1 + 1024);
  }

#define SOFTMAX_PV(SV, M_I, L_I, ACC, DIAG)                                     \
  {                                                                             \
    float tmax_ = -3e38f;                                                       \
    if (DIAG) {                                                                 \
      _Pragma("unroll") for (int nc = 0; nc < 4; ++nc) {                        \
        _Pragma("unroll") for (int i = 0; i < 4; ++i) {                         \
          float v_ = SV[nc][i];                                                 \
          if ((nc * 16 + lq * 4 + i) > (w * 16 + l16)) v_ = -3e38f;             \
          SV[nc][i] = v_;                                                       \
          tmax_ = fmaxf(tmax_, v_);                                             \
        }                                                                       \
      }                                                                         \
    } else {                                                                    \
      _Pragma("unroll") for (int nc = 0; nc < 4; ++nc)                          \
        tmax_ = fmaxf(tmax_, fmaxf(fmaxf(SV[nc][0], SV[nc][1]),                 \
                                   fmaxf(SV[nc][2], SV[nc][3])));               \
    }                                                                           \
    tmax_ = fmaxf(tmax_, __shfl_xor(tmax_, 16, 64));                            \
    tmax_ = fmaxf(tmax_, __shfl_xor(tmax_, 32, 64));                            \
    if (!__all(tmax_ <= M_I + THR_RAW)) {                                       \
      const float mn_ = fmaxf(M_I, tmax_);                                      \
      const float alpha_ = EXP2((M_I - mn_) * C_SCL);                           \
      M_I = mn_;                                                                \
      L_I *= alpha_;                                                            \
      float ab_[4];                                                             \
      _Pragma("unroll") for (int i = 0; i < 4; ++i)                             \
        ab_[i] = __shfl(alpha_, lq * 4 + i, 64);                                \
      _Pragma("unroll") for (int d4 = 0; d4 < 4; ++d4)                          \
        _Pragma("unroll") for (int i = 0; i < 4; ++i)                           \
          ACC[d4][i] *= ab_[i];                                                 \
    }                                                                           \
    const float mc_ = M_I * C_SCL;                                              \
    float rsum_ = 0.f;                                                          \
    short8 pa0_, pa1_;                                                          \
    _Pragma("unroll") for (int nc = 0; nc < 4; ++nc) {                          \
      _Pragma("unroll") for (int i = 0; i < 4; ++i) {                           \
        float pv_ = EXP2(__builtin_fmaf(SV[nc][i], C_SCL, -mc_));               \
        rsum_ += pv_;                                                           \
        uint16_t ph_ = f2bf_hw(pv_);                                            \
        if (nc < 2) pa0_[nc * 4 + i] = (short)ph_;                              \
        else        pa1_[(nc - 2) * 4 + i] = (short)ph_;                        \
      }                                                                         \
    }                                                                           \
    rsum_ += __shfl_xor(rsum_, 16, 64);                                         \
    rsum_ += __shfl_xor(rsum_, 32, 64);                                         \
    L_I += rsum_;                                                               \
    _Pragma("unroll") for (int d4 = 0; d4 < 4; ++d4) {                          \
      const int drow_ = d4 * 16 + l16;                                          \
      const int xr_ = (drow_ >> 3) & 7;                                         \
      short8 vb0_ = *reinterpret_cast<const short8*>(&Vt[drow_ * 72 + (((2 * lq) ^ xr_) * 8)]); \
      short8 vb1_ = *reinterpret_cast<const short8*>(&Vt[drow_ * 72 + (((2 * lq + 1) ^ xr_) * 8)]); \
      ACC[d4] = __builtin_amdgcn_mfma_f32_16x16x32_bf16(pa0_, vb0_, ACC[d4], 0, 0, 0); \
      ACC[d4] = __builtin_amdgcn_mfma_f32_16x16x32_bf16(pa1_, vb1_, ACC[d4], 0, 0, 0); \
    }                                                                           \
  }

  for (int jt = 0; jt < ntiles; ++jt) {
    // --- commit staged regs to LDS (prev compute finished at loop-end barrier) ---
    *reinterpret_cast<short8*>(&Ks[ka0]) = rk0;
    *reinterpret_cast<short8*>(&Ks[ka1]) = rk1;
#pragma unroll
    for (int j = 0; j < 8; ++j) Vt[(d0 + j) * 72 + vcol0] = (uint16_t)rv0[j];
#pragma unroll
    for (int j = 0; j < 8; ++j) Vt[(d0 + j) * 72 + vcol1] = (uint16_t)rv1[j];
    // --- issue next tile's global loads; latency hides under this tile's compute ---
    if (jt + 1 < ntiles) {
      const size_t g0 = ((size_t)(b * NSEQ + (jt + 1) * 64 + r0)) * QKV_LD + 1024 + h * 64 + d0;
      const size_t g1 = ((size_t)(b * NSEQ + (jt + 1) * 64 + r0 + 32)) * QKV_LD + 1024 + h * 64 + d0;
      rk0 = *reinterpret_cast<const short8*>(qkv + g0);
      rv0 = *reinterpret_cast<const short8*>(qkv + g0 + 1024);
      rk1 = *reinterpret_cast<const short8*>(qkv + g1);
      rv1 = *reinterpret_cast<const short8*>(qkv + g1 + 1024);
    }
    __syncthreads();

    // --- tile B: S^T = K Q^T, softmax, PV ---
    {
      f32x4 sv[4];
#pragma unroll
      for (int nc = 0; nc < 4; ++nc) {
        short8 kb0 = *reinterpret_cast<const short8*>(&Ks[(nc * 16 + l16) * 72 + lq * 8]);
        short8 kb1 = *reinterpret_cast<const short8*>(&Ks[(nc * 16 + l16) * 72 + 32 + lq * 8]);
        f32x4 s = fzero;
        s = __builtin_amdgcn_mfma_f32_16x16x32_bf16(kb0, qaB0, s, 0, 0, 0);
        s = __builtin_amdgcn_mfma_f32_16x16x32_bf16(kb1, qaB1, s, 0, 0, 0);
        sv[nc] = s;
      }
      SOFTMAX_PV(sv, mB, lB, accB, jt == qtB);
    }

    // --- tile A (active while jt <= qtA) ---
    if (jt <= qtA) {
      f32x4 sv[4];
#pragma unroll
      for (int nc = 0; nc < 4; ++nc) {
        short8 kb0 = *reinterpret_cast<const short8*>(&Ks[(nc * 16 + l16) * 72 + lq * 8]);
        short8 kb1 = *reinterpret_cast<const short8*>(&Ks[(nc * 16 + l16) * 72 + 32 + lq * 8]);
        f32x4 s = fzero;
        s = __builtin_amdgcn_mfma_f32_16x16x32_bf16(kb0, qaA0, s, 0, 0, 0);
        s = __builtin_amdgcn_mfma_f32_16x16x32_bf16(kb1, qaA1, s, 0, 0, 0);
        sv[nc] = s;
      }
      SOFTMAX_PV(sv, mA, lA, accA, jt == qtA);
    }

    __syncthreads();   // protect Ks/Vt before next stage-commit
  }

  // epilogue: l for acc row q = lq*4 + i lives at lane l16 = q
  {
    float lb4[4];
#pragma unroll
    for (int i = 0; i < 4; ++i) lb4[i] = __shfl(lA, lq * 4 + i, 64);
    const size_t orow = (size_t)(b * NSEQ) + qtA * 64 + w * 16 + lq * 4;
#pragma unroll
    for (int d4 = 0; d4 < 4; ++d4)
#pragma unroll
      for (int i = 0; i < 4; ++i)
        outb[(orow + i) * (size_t)DMODEL + h * 64 + d4 * 16 + l16] = f2bf_hw(accA[d4][i] / lb4[i]);
  }
  {
    float lb4[4];
#pragma unroll
    for (int i = 0; i < 4; ++i) lb4[i] = __shfl(lB, lq * 4 + i, 64);
    const size_t orow = (size_t)(b * NSEQ) + qtB * 64 + w * 16 + lq * 4;
#pragma unroll
    for (int d4 = 0; d4 < 4; ++d4)
#pragma unroll
      for (int i = 0; i < 4; ++i)
        outb[(orow + i) * (size_t)DMODEL + h * 64 + d4 * 16 + l16] = f2bf_hw(accB[d4][i] / lb4[i]);
  }
}

extern "C" void kernel_launch(void* const* d_in, const int* in_sizes, int n_in,
                              void* d_out, int out_size, void* d_ws, size_t ws_size,
                              hipStream_t stream) {
  const float* x      = (const float*)d_in[0];
  const float* w_attn = (const float*)d_in[1];
  const float* w_proj = (const float*)d_in[2];
  const float* b_proj = (const float*)d_in[3];

  uint16_t* xb    = (uint16_t*)d_ws;                    // [8192][1024]
  uint16_t* wat   = xb   + (size_t)MTOT * DMODEL;       // [3072][1024] (w_attn^T)
  uint16_t* wpt   = wat  + (size_t)3072 * 1024;         // [1024][1024] (w_proj^T)
  uint16_t* qkvb  = wpt  + (size_t)1024 * 1024;         // [8192][3072]
  uint16_t* attnb = qkvb + (size_t)MTOT * QKV_LD;       // [8192][1024]

  prep_k<<<2048 + 3072 + 1024, 256, 0, stream>>>(x, xb, w_attn, wat, w_proj, wpt);

  gemm_bt_k<true><<<dim3(3072 / 128, MTOT / 128), 256, 0, stream>>>(
      xb, wat, qkvb, nullptr, MTOT, 3072, 1024);

  attn_fwd_k<<<BQ * NHEAD * 16, 256, 0, stream>>>(qkvb, attnb);

  gemm_bt_k<false><<<dim3(1024 / 128, MTOT / 128), 256, 0, stream>>>(
      attnb, wpt, d_out, b_proj, MTOT, 1024, 1024);
}

// Round 18
// 178.808 us; speedup vs baseline: 1.1149x; 1.0069x over previous
//
#include <hip/hip_runtime.h>
#include <hip/hip_bf16.h>
#include <stdint.h>

typedef short short8 __attribute__((ext_vector_type(8)));
typedef float f32x4 __attribute__((ext_vector_type(4)));

#define BQ 4
#define NSEQ 2048
#define DMODEL 1024
#define NHEAD 16
#define HDIM 64
#define MTOT 8192          // BQ*NSEQ
#define QKV_LD 3072

#if __has_builtin(__builtin_amdgcn_exp2f)
#define EXP2(x) __builtin_amdgcn_exp2f(x)
#else
#define EXP2(x) exp2f(x)
#endif
#define C_SCL 0.18033688f   // 0.125 * log2(e)
#define THR_RAW 16.635532f  // 3.0 / C_SCL : defer-max threshold (P bounded by 2^3)

__device__ __forceinline__ uint16_t f2bf(float f) {
  uint32_t u = __builtin_bit_cast(uint32_t, f);
  uint32_t r = (u + 0x7FFFu + ((u >> 16) & 1u)) >> 16;
  return (uint16_t)r;
}
// hardware RNE convert (v_cvt_pk_bf16_f32 after compiler fusion)
__device__ __forceinline__ uint16_t f2bf_hw(float f) {
  __hip_bfloat16 h = __float2bfloat16(f);
  return __builtin_bit_cast(uint16_t, h);
}

// Single prep kernel = cast(x) + transpose(w_attn) + transpose(w_proj).
__global__ void prep_k(const float* __restrict__ x, uint16_t* __restrict__ xb,
                       const float* __restrict__ w_attn, uint16_t* __restrict__ wat,
                       const float* __restrict__ w_proj, uint16_t* __restrict__ wpt) {
  __shared__ float tile[32][33];
  const int bid = blockIdx.x;
  if (bid < 2048) {
    // cast x [8192*1024] f32 -> bf16
    int idx = (bid * 256 + threadIdx.x) * 4;
    const int stride = 2048 * 256 * 4;
    for (int i = idx; i < MTOT * DMODEL; i += stride) {
      float4 v = *reinterpret_cast<const float4*>(x + i);
      ushort4 o;
      o.x = f2bf(v.x); o.y = f2bf(v.y); o.z = f2bf(v.z); o.w = f2bf(v.w);
      *reinterpret_cast<ushort4*>(xb + i) = o;
    }
    return;
  }
  // transpose+cast: in [K=1024][N] f32 -> out [N][K] bf16
  const float* in; uint16_t* out; int N, t;
  if (bid < 2048 + 3072) { in = w_attn; out = wat; N = 3072; t = bid - 2048; }
  else                   { in = w_proj; out = wpt; N = 1024; t = bid - 5120; }
  const int K = 1024;
  const int nb = N / 32;
  const int n0 = (t % nb) * 32;
  const int k0 = (t / nb) * 32;
  const int tx = threadIdx.x & 31;
  const int ty = threadIdx.x >> 5;
#pragma unroll
  for (int r = 0; r < 4; ++r)
    tile[ty + r * 8][tx] = in[(size_t)(k0 + ty + r * 8) * N + n0 + tx];
  __syncthreads();
#pragma unroll
  for (int r = 0; r < 4; ++r)
    out[(size_t)(n0 + ty + r * 8) * K + k0 + tx] = f2bf(tile[tx][ty + r * 8]);
}

// C[M,N] = A[M,K] @ BT[N,K]^T ; A,BT bf16 row-major. 128x128 tile, BK=64.
// Halves the K-iterations (32->16) so the structure's defining stall (vmcnt(0)
// drain before each barrier) amortizes over 2x MFMA work; LDS 32KB keeps
// 3 blocks/CU. Bank fix per m173: pre-swizzled global source — row r's LDS slot
// s holds global k-chunk s ^ (r&7); reader uses slot (kk*4+lq) ^ (l16&7).
// Measured round 17: GEMMs -10% vs BK=32.
template <bool BF16_OUT>
__global__ void __launch_bounds__(256, 3)
gemm_bt_k(const uint16_t* __restrict__ A, const uint16_t* __restrict__ BT,
          void* __restrict__ Cout, const float* __restrict__ bias,
          int M, int N, int K) {
  __shared__ uint16_t As[128 * 64];
  __shared__ uint16_t Bs[128 * 64];
  const int tid = threadIdx.x;
  const int lane = tid & 63;
  const int wave = tid >> 6;
  const int wr = wave >> 1, wc = wave & 1;   // wave -> 64x64 quadrant
  const int brow = blockIdx.y * 128;
  const int bcol = blockIdx.x * 128;
  const int l16 = lane & 15;
  const int lq = lane >> 4;

  f32x4 acc[4][4];
  const f32x4 fzero = {0.f, 0.f, 0.f, 0.f};
#pragma unroll
  for (int i = 0; i < 4; ++i)
#pragma unroll
    for (int j = 0; j < 4; ++j) acc[i][j] = fzero;

  // staging: 1024 16B-chunks per 128x64 tile; chunk c -> row c>>3, slot c&7;
  // slot holds global k-chunk (c&7) ^ (row&7). LDS linear at c*8 elems.
  size_t gA0, gA1, gA2, gA3, gB0, gB1, gB2, gB3;
  int ls0, ls1, ls2, ls3;
  {
    int c0 = tid, c1 = tid + 256, c2 = tid + 512, c3 = tid + 768;
    int r0 = c0 >> 3, r1 = c1 >> 3, r2 = c2 >> 3, r3 = c3 >> 3;
    int k0 = (c0 & 7) ^ (r0 & 7), k1 = (c1 & 7) ^ (r1 & 7);
    int k2 = (c2 & 7) ^ (r2 & 7), k3 = (c3 & 7) ^ (r3 & 7);
    gA0 = (size_t)(brow + r0) * K + k0 * 8;  gB0 = (size_t)(bcol + r0) * K + k0 * 8;
    gA1 = (size_t)(brow + r1) * K + k1 * 8;  gB1 = (size_t)(bcol + r1) * K + k1 * 8;
    gA2 = (size_t)(brow + r2) * K + k2 * 8;  gB2 = (size_t)(bcol + r2) * K + k2 * 8;
    gA3 = (size_t)(brow + r3) * K + k3 * 8;  gB3 = (size_t)(bcol + r3) * K + k3 * 8;
    ls0 = c0 * 8; ls1 = c1 * 8; ls2 = c2 * 8; ls3 = c3 * 8;
  }

#define GLD(PTR, OFF, LDSARR, LS)                                               \
  __builtin_amdgcn_global_load_lds(                                             \
      (const __attribute__((address_space(1))) void*)((PTR) + (OFF)),           \
      (__attribute__((address_space(3))) void*)&LDSARR[LS], 16, 0, 0)

  for (int kt = 0; kt < K; kt += 64) {
    GLD(A, gA0 + kt, As, ls0);
    GLD(A, gA1 + kt, As, ls1);
    GLD(A, gA2 + kt, As, ls2);
    GLD(A, gA3 + kt, As, ls3);
    GLD(BT, gB0 + kt, Bs, ls0);
    GLD(BT, gB1 + kt, Bs, ls1);
    GLD(BT, gB2 + kt, Bs, ls2);
    GLD(BT, gB3 + kt, Bs, ls3);
    __syncthreads();   // implicit vmcnt(0) drain before barrier (once per 64 K)
#pragma unroll
    for (int kk = 0; kk < 2; ++kk) {
      short8 af[4], bfr[4];
#pragma unroll
      for (int r = 0; r < 4; ++r) {
        const int rowA = wr * 64 + r * 16 + l16;
        const int rowB = wc * 64 + r * 16 + l16;
        const int slot = (kk * 4 + lq) ^ (l16 & 7);   // (row&7) == (l16&7)
        af[r]  = *reinterpret_cast<const short8*>(&As[rowA * 64 + slot * 8]);
        bfr[r] = *reinterpret_cast<const short8*>(&Bs[rowB * 64 + slot * 8]);
      }
#pragma unroll
      for (int r = 0; r < 4; ++r)
#pragma unroll
        for (int c = 0; c < 4; ++c)
          acc[r][c] = __builtin_amdgcn_mfma_f32_16x16x32_bf16(af[r], bfr[c], acc[r][c], 0, 0, 0);
    }
    __syncthreads();
  }
#undef GLD

#pragma unroll
  for (int r = 0; r < 4; ++r) {
    const int row0 = brow + wr * 64 + r * 16 + lq * 4;
#pragma unroll
    for (int c = 0; c < 4; ++c) {
      const int col = bcol + wc * 64 + c * 16 + l16;
#pragma unroll
      for (int i = 0; i < 4; ++i) {
        if constexpr (BF16_OUT)
          reinterpret_cast<uint16_t*>(Cout)[(size_t)(row0 + i) * N + col] = f2bf_hw(acc[r][c][i]);
        else
          reinterpret_cast<float*>(Cout)[(size_t)(row0 + i) * N + col] = acc[r][c][i] + bias[col];
      }
    }
  }
}

// Flash attention, causal. qkv [MTOT][3072] bf16 (q|k|v), out [MTOT][1024] bf16.
// Round-13 structure (best measured). ROUND-18: tree-reassociated softmax
// reductions — rsum was a 16-deep dependent fadd chain (~64 cyc, fadd not
// reassociable without fast-math), tmax cross-nc was 6-deep; both now depth-4.
// Latency-bound kernel -> dependent-chain cuts are on the critical path.
__global__ void __launch_bounds__(256, 3)
attn_fwd_k(const uint16_t* __restrict__ qkv, uint16_t* __restrict__ outb) {
  const int obid = blockIdx.x;
  const int bid = (obid & 7) * 128 + (obid >> 3);   // T1: contiguous 128-block chunk per XCD
  const int p = bid & 15;
  const int h = (bid >> 4) & 15;
  const int b = bid >> 8;
  const int qtA = p;
  const int qtB = 31 - p;
  const int tid = threadIdx.x;
  const int lane = tid & 63;
  const int w = tid >> 6;
  const int l16 = lane & 15;
  const int lq = lane >> 4;

  __shared__ uint16_t Ks[64 * 72];         // [token][d], stride 72
  __shared__ uint16_t Vt[64 * 72];         // [d][sigma-permuted token], stride 72

  // Q fragments for both q-tiles (row=l16, k=8*lq+j per 32-d chunk)
  short8 qaA0, qaA1, qaB0, qaB1;
  {
    const size_t baseA = ((size_t)(b * NSEQ + qtA * 64 + w * 16 + l16)) * QKV_LD + h * 64 + lq * 8;
    const size_t baseB = ((size_t)(b * NSEQ + qtB * 64 + w * 16 + l16)) * QKV_LD + h * 64 + lq * 8;
    qaA0 = *reinterpret_cast<const short8*>(qkv + baseA);
    qaA1 = *reinterpret_cast<const short8*>(qkv + baseA + 32);
    qaB0 = *reinterpret_cast<const short8*>(qkv + baseB);
    qaB1 = *reinterpret_cast<const short8*>(qkv + baseB + 32);
  }

  float mA = -1e30f, lA = 0.f, mB = -1e30f, lB = 0.f;
  f32x4 accA[4], accB[4];
  const f32x4 fzero = {0.f, 0.f, 0.f, 0.f};
#pragma unroll
  for (int i = 0; i < 4; ++i) { accA[i] = fzero; accB[i] = fzero; }

  // staging geometry: 512 chunks, chunk c -> token row c>>3, d-off (c&7)*8
  const int r0 = tid >> 3, d0 = (tid & 7) * 8;
  const int ka0 = r0 * 72 + d0;
  const int ka1 = (r0 + 32) * 72 + d0;
  const int lqt = (r0 >> 2) & 3;
  const int nc0 = r0 >> 4;
  const int m0 = d0 >> 3;
  const int jo = (nc0 & 1) * 4 + (r0 & 3);
  const int vcol0 = (((2 * lqt) ^ m0) * 8) + jo;        // token r0  -> pa0 chunk
  const int vcol1 = (((2 * lqt + 1) ^ m0) * 8) + jo;    // token r0+32 -> pa1 chunk

  const int ntiles = qtB + 1;
  short8 rk0, rk1, rv0, rv1;
  {
    const size_t g0 = ((size_t)(b * NSEQ + r0)) * QKV_LD + 1024 + h * 64 + d0;
    const size_t g1 = ((size_t)(b * NSEQ + r0 + 32)) * QKV_LD + 1024 + h * 64 + d0;
    rk0 = *reinterpret_cast<const short8*>(qkv + g0);
    rv0 = *reinterpret_cast<const short8*>(qkv + g0 + 1024);
    rk1 = *reinterpret_cast<const short8*>(qkv + g1);
    rv1 = *reinterpret_cast<const short8*>(qkv + g1 + 1024);
  }

#define SOFTMAX_PV(SV, M_I, L_I, ACC, DIAG)                                     \
  {                                                                             \
    float tmax_;                                                                \
    if (DIAG) {                                                                 \
      float tm_[4];                                                             \
      _Pragma("unroll") for (int nc = 0; nc < 4; ++nc) {                        \
        float a_ = -3e38f, b_ = -3e38f;                                         \
        _Pragma("unroll") for (int i = 0; i < 4; ++i) {                         \
          float v_ = SV[nc][i];                                                 \
          if ((nc * 16 + lq * 4 + i) > (w * 16 + l16)) v_ = -3e38f;             \
          SV[nc][i] = v_;                                                       \
          if (i < 2) a_ = fmaxf(a_, v_); else b_ = fmaxf(b_, v_);               \
        }                                                                       \
        tm_[nc] = fmaxf(a_, b_);                                                \
      }                                                                         \
      tmax_ = fmaxf(fmaxf(tm_[0], tm_[1]), fmaxf(tm_[2], tm_[3]));              \
    } else {                                                                    \
      float tm_[4];                                                             \
      _Pragma("unroll") for (int nc = 0; nc < 4; ++nc)                          \
        tm_[nc] = fmaxf(fmaxf(SV[nc][0], SV[nc][1]),                            \
                        fmaxf(SV[nc][2], SV[nc][3]));                           \
      tmax_ = fmaxf(fmaxf(tm_[0], tm_[1]), fmaxf(tm_[2], tm_[3]));              \
    }                                                                           \
    tmax_ = fmaxf(tmax_, __shfl_xor(tmax_, 16, 64));                            \
    tmax_ = fmaxf(tmax_, __shfl_xor(tmax_, 32, 64));                            \
    if (!__all(tmax_ <= M_I + THR_RAW)) {                                       \
      const float mn_ = fmaxf(M_I, tmax_);                                      \
      const float alpha_ = EXP2((M_I - mn_) * C_SCL);                           \
      M_I = mn_;                                                                \
      L_I *= alpha_;                                                            \
      float ab_[4];                                                             \
      _Pragma("unroll") for (int i = 0; i < 4; ++i)                             \
        ab_[i] = __shfl(alpha_, lq * 4 + i, 64);                                \
      _Pragma("unroll") for (int d4 = 0; d4 < 4; ++d4)                          \
        _Pragma("unroll") for (int i = 0; i < 4; ++i)                           \
          ACC[d4][i] *= ab_[i];                                                 \
    }                                                                           \
    const float mc_ = M_I * C_SCL;                                              \
    float rs_[4];                                                               \
    short8 pa0_, pa1_;                                                          \
    _Pragma("unroll") for (int nc = 0; nc < 4; ++nc) {                          \
      float pvv_[4];                                                            \
      _Pragma("unroll") for (int i = 0; i < 4; ++i) {                           \
        float pv_ = EXP2(__builtin_fmaf(SV[nc][i], C_SCL, -mc_));               \
        pvv_[i] = pv_;                                                          \
        uint16_t ph_ = f2bf_hw(pv_);                                            \
        if (nc < 2) pa0_[nc * 4 + i] = (short)ph_;                              \
        else        pa1_[(nc - 2) * 4 + i] = (short)ph_;                        \
      }                                                                         \
      rs_[nc] = (pvv_[0] + pvv_[1]) + (pvv_[2] + pvv_[3]);                      \
    }                                                                           \
    float rsum_ = (rs_[0] + rs_[1]) + (rs_[2] + rs_[3]);                        \
    rsum_ += __shfl_xor(rsum_, 16, 64);                                         \
    rsum_ += __shfl_xor(rsum_, 32, 64);                                         \
    L_I += rsum_;                                                               \
    _Pragma("unroll") for (int d4 = 0; d4 < 4; ++d4) {                          \
      const int drow_ = d4 * 16 + l16;                                          \
      const int xr_ = (drow_ >> 3) & 7;                                         \
      short8 vb0_ = *reinterpret_cast<const short8*>(&Vt[drow_ * 72 + (((2 * lq) ^ xr_) * 8)]); \
      short8 vb1_ = *reinterpret_cast<const short8*>(&Vt[drow_ * 72 + (((2 * lq + 1) ^ xr_) * 8)]); \
      ACC[d4] = __builtin_amdgcn_mfma_f32_16x16x32_bf16(pa0_, vb0_, ACC[d4], 0, 0, 0); \
      ACC[d4] = __builtin_amdgcn_mfma_f32_16x16x32_bf16(pa1_, vb1_, ACC[d4], 0, 0, 0); \
    }                                                                           \
  }

  for (int jt = 0; jt < ntiles; ++jt) {
    // --- commit staged regs to LDS (prev compute finished at loop-end barrier) ---
    *reinterpret_cast<short8*>(&Ks[ka0]) = rk0;
    *reinterpret_cast<short8*>(&Ks[ka1]) = rk1;
#pragma unroll
    for (int j = 0; j < 8; ++j) Vt[(d0 + j) * 72 + vcol0] = (uint16_t)rv0[j];
#pragma unroll
    for (int j = 0; j < 8; ++j) Vt[(d0 + j) * 72 + vcol1] = (uint16_t)rv1[j];
    // --- issue next tile's global loads; latency hides under this tile's compute ---
    if (jt + 1 < ntiles) {
      const size_t g0 = ((size_t)(b * NSEQ + (jt + 1) * 64 + r0)) * QKV_LD + 1024 + h * 64 + d0;
      const size_t g1 = ((size_t)(b * NSEQ + (jt + 1) * 64 + r0 + 32)) * QKV_LD + 1024 + h * 64 + d0;
      rk0 = *reinterpret_cast<const short8*>(qkv + g0);
      rv0 = *reinterpret_cast<const short8*>(qkv + g0 + 1024);
      rk1 = *reinterpret_cast<const short8*>(qkv + g1);
      rv1 = *reinterpret_cast<const short8*>(qkv + g1 + 1024);
    }
    __syncthreads();

    // --- tile B: S^T = K Q^T, softmax, PV ---
    {
      f32x4 sv[4];
#pragma unroll
      for (int nc = 0; nc < 4; ++nc) {
        short8 kb0 = *reinterpret_cast<const short8*>(&Ks[(nc * 16 + l16) * 72 + lq * 8]);
        short8 kb1 = *reinterpret_cast<const short8*>(&Ks[(nc * 16 + l16) * 72 + 32 + lq * 8]);
        f32x4 s = fzero;
        s = __builtin_amdgcn_mfma_f32_16x16x32_bf16(kb0, qaB0, s, 0, 0, 0);
        s = __builtin_amdgcn_mfma_f32_16x16x32_bf16(kb1, qaB1, s, 0, 0, 0);
        sv[nc] = s;
      }
      SOFTMAX_PV(sv, mB, lB, accB, jt == qtB);
    }

    // --- tile A (active while jt <= qtA) ---
    if (jt <= qtA) {
      f32x4 sv[4];
#pragma unroll
      for (int nc = 0; nc < 4; ++nc) {
        short8 kb0 = *reinterpret_cast<const short8*>(&Ks[(nc * 16 + l16) * 72 + lq * 8]);
        short8 kb1 = *reinterpret_cast<const short8*>(&Ks[(nc * 16 + l16) * 72 + 32 + lq * 8]);
        f32x4 s = fzero;
        s = __builtin_amdgcn_mfma_f32_16x16x32_bf16(kb0, qaA0, s, 0, 0, 0);
        s = __builtin_amdgcn_mfma_f32_16x16x32_bf16(kb1, qaA1, s, 0, 0, 0);
        sv[nc] = s;
      }
      SOFTMAX_PV(sv, mA, lA, accA, jt == qtA);
    }

    __syncthreads();   // protect Ks/Vt before next stage-commit
  }

  // epilogue: l for acc row q = lq*4 + i lives at lane l16 = q
  {
    float lb4[4];
#pragma unroll
    for (int i = 0; i < 4; ++i) lb4[i] = __shfl(lA, lq * 4 + i, 64);
    const size_t orow = (size_t)(b * NSEQ) + qtA * 64 + w * 16 + lq * 4;
#pragma unroll
    for (int d4 = 0; d4 < 4; ++d4)
#pragma unroll
      for (int i = 0; i < 4; ++i)
        outb[(orow + i) * (size_t)DMODEL + h * 64 + d4 * 16 + l16] = f2bf_hw(accA[d4][i] / lb4[i]);
  }
  {
    float lb4[4];
#pragma unroll
    for (int i = 0; i < 4; ++i) lb4[i] = __shfl(lB, lq * 4 + i, 64);
    const size_t orow = (size_t)(b * NSEQ) + qtB * 64 + w * 16 + lq * 4;
#pragma unroll
    for (int d4 = 0; d4 < 4; ++d4)
#pragma unroll
      for (int i = 0; i < 4; ++i)
        outb[(orow + i) * (size_t)DMODEL + h * 64 + d4 * 16 + l16] = f2bf_hw(accB[d4][i] / lb4[i]);
  }
}

extern "C" void kernel_launch(void* const* d_in, const int* in_sizes, int n_in,
                              void* d_out, int out_size, void* d_ws, size_t ws_size,
                              hipStream_t stream) {
  const float* x      = (const float*)d_in[0];
  const float* w_attn = (const float*)d_in[1];
  const float* w_proj = (const float*)d_in[2];
  const float* b_proj = (const float*)d_in[3];

  uint16_t* xb    = (uint16_t*)d_ws;                    // [8192][1024]
  uint16_t* wat   = xb   + (size_t)MTOT * DMODEL;       // [3072][1024] (w_attn^T)
  uint16_t* wpt   = wat  + (size_t)3072 * 1024;         // [1024][1024] (w_proj^T)
  uint16_t* qkvb  = wpt  + (size_t)1024 * 1024;         // [8192][3072]
  uint16_t* attnb = qkvb + (size_t)MTOT * QKV_LD;       // [8192][1024]

  prep_k<<<2048 + 3072 + 1024, 256, 0, stream>>>(x, xb, w_attn, wat, w_proj, wpt);

  gemm_bt_k<true><<<dim3(3072 / 128, MTOT / 128), 256, 0, stream>>>(
      xb, wat, qkvb, nullptr, MTOT, 3072, 1024);

  attn_fwd_k<<<BQ * NHEAD * 16, 256, 0, stream>>>(qkvb, attnb);

  gemm_bt_k<false><<<dim3(1024 / 128, MTOT / 128), 256, 0, stream>>>(
      attnb, wpt, d_out, b_proj, MTOT, 1024, 1024);
}